// Round 15
// baseline (284.143 us; speedup 1.0000x reference)
//
#include <hip/hip_runtime.h>
#include <math.h>

// ---------------------------------------------------------------------------
// TopoGAT: 2-layer GAT on MI355X.
// R10: fixed-capacity bucket CSR build; padded CSR with rowptr/rowEnd.
// R5:  gather tables h1/g in bf16.
// R14: CSR build — k_bin BIN_CHUNK=4096; k_fill2 512thr + uint4 count pass.
// R21/R22: agg kernels -> 1 wave-wide csr load + all gathers up-front.
// R24/R25: agg kernels -> 2 nodes/wave: agg1 ~48.5, agg2 <48. VERIFIED.
// R26 FAILED: W1-from-global (34.8KB > 32KB L1 -> L2 latency per k).
// R27: WS bf16 in LDS (52.2KB, 3 blocks/CU): xform1 -> ~49.5. VERIFIED BEST.
// R28 FAILED: XT bf16 too: occupancy 23->29% but +8 unpacks/k (+25% VALU)
//      ate the gain; xform1 -> ~51.5. LESSON: unpack-per-FMA ratio is the
//      binding constraint at this occupancy; XT stays fp32.
// R29: xform1 REVERTED to R27 exact. xform2 gets the twice-verified
//      WS-bf16 pattern (W2 packed pairs): LDS 26.25 -> 21.25KB (6->7
//      blocks/CU), W-LDS bytes/k halved. MFMA xform1 remains the only
//      big lever left; deliberately not risked this round.
// ---------------------------------------------------------------------------

#define NBUK_MAX 512
#define BIN_CHUNK 4096
#define BUK_CAP 4608

typedef unsigned short ushort_t;

__device__ inline unsigned int f2bf(float f) {  // RNE fp32->bf16
    unsigned int u = __float_as_uint(f);
    u += 0x7FFFu + ((u >> 16) & 1u);
    return u >> 16;
}
__device__ inline float bf_lo(unsigned int u) {
    return __uint_as_float(u << 16);
}
__device__ inline float bf_hi(unsigned int u) {
    return __uint_as_float(u & 0xFFFF0000u);
}
__device__ inline float lrelu_exp(float q) {
    return __expf(q >= 0.f ? q : 0.2f * q);
}

__device__ inline int wave_incl_scan(int v, int lane) {
    #pragma unroll
    for (int ofs = 1; ofs < 64; ofs <<= 1) {
        int t = __shfl_up(v, ofs);
        if (lane >= ofs) v += t;
    }
    return v;
}

// Bin edges into fixed-capacity bucket regions of tmp. One global atomic per
// (block,bucket); packed word = (src<<8) | (dst&255). 16 edges/thread via
// int4 loads; dst stashed in registers across the reservation barrier.
__global__ __launch_bounds__(256) void k_bin(const int* __restrict__ src,
                                             const int* __restrict__ dst,
                                             int* __restrict__ gCursor,
                                             unsigned int* __restrict__ tmp,
                                             int E, int NBUK) {
    __shared__ int lcnt[NBUK_MAX];
    __shared__ int lcur[NBUK_MAX];
    int tid = threadIdx.x;
    int base = blockIdx.x * BIN_CHUNK;
    for (int i = tid; i < NBUK; i += 256) lcnt[i] = 0;
    __syncthreads();
    int d[16];
    #pragma unroll
    for (int q = 0; q < 4; q++) {
        int e = base + q * 1024 + 4 * tid;
        if (e + 3 < E) {
            int4 v = *(const int4*)&dst[e];
            d[4 * q + 0] = v.x; d[4 * q + 1] = v.y;
            d[4 * q + 2] = v.z; d[4 * q + 3] = v.w;
        } else {
            #pragma unroll
            for (int k = 0; k < 4; k++)
                d[4 * q + k] = (e + k < E) ? dst[e + k] : -1;
        }
    }
    #pragma unroll
    for (int k = 0; k < 16; k++)
        if (d[k] >= 0) atomicAdd(&lcnt[d[k] >> 8], 1);
    __syncthreads();
    for (int b = tid; b < NBUK; b += 256) {
        int c = lcnt[b];
        lcur[b] = c ? b * BUK_CAP + atomicAdd(&gCursor[b], c) : 0;
    }
    __syncthreads();
    #pragma unroll
    for (int q = 0; q < 4; q++) {
        int e = base + q * 1024 + 4 * tid;
        int s[4];
        if (e + 3 < E) {
            int4 v = *(const int4*)&src[e];
            s[0] = v.x; s[1] = v.y; s[2] = v.z; s[3] = v.w;
        } else {
            #pragma unroll
            for (int k = 0; k < 4; k++)
                s[k] = (e + k < E) ? src[e + k] : 0;
        }
        #pragma unroll
        for (int k = 0; k < 4; k++) {
            int dd = d[4 * q + k];
            if (dd >= 0) {
                int p = atomicAdd(&lcur[dd >> 8], 1);
                tmp[p] = ((unsigned int)s[k] << 8) | (unsigned int)(dd & 255);
            }
        }
    }
}

// Exact CSR fill within a bucket (padded layout, base = b*BUK_CAP).
// 512 threads; count pass reads tmp as uint4.
__global__ __launch_bounds__(512) void k_fill2(const unsigned int* __restrict__ tmp,
                                               const int* __restrict__ gCursor,
                                               int* __restrict__ rowptr,
                                               int* __restrict__ rowEnd,
                                               int* __restrict__ csr, int N) {
    __shared__ int cnt[256];
    __shared__ int cur[256];
    __shared__ int wsum[4];
    int b = blockIdx.x, tid = threadIdx.x;
    int e0 = b * BUK_CAP;
    int cnt_e = gCursor[b];       // bucket edge count
    int e1 = e0 + cnt_e;
    if (tid < 256) cnt[tid] = 0;
    __syncthreads();
    {   // count pass: uint4 over the bulk (e0 is 16B-aligned: BUK_CAP*4 % 16 == 0)
        int nq = cnt_e >> 2;
        const uint4* t4 = (const uint4*)(tmp + e0);
        for (int q = tid; q < nq; q += 512) {
            uint4 v = t4[q];
            atomicAdd(&cnt[v.x & 255u], 1);
            atomicAdd(&cnt[v.y & 255u], 1);
            atomicAdd(&cnt[v.z & 255u], 1);
            atomicAdd(&cnt[v.w & 255u], 1);
        }
        for (int i = (nq << 2) + tid; i < cnt_e; i += 512)
            atomicAdd(&cnt[tmp[e0 + i] & 255u], 1);
    }
    __syncthreads();
    if (tid < 256) {
        int lane = tid & 63, wv = tid >> 6;
        int v = cnt[tid];
        int incl = wave_incl_scan(v, lane);
        if (lane == 63) wsum[wv] = incl;
        cnt[tid] = incl - v;  // stash exclusive-within-wave
    }
    __syncthreads();
    if (tid < 256) {
        int wv = tid >> 6;
        int woff = 0;
        for (int i = 0; i < wv; i++) woff += wsum[i];
        int excl = woff + cnt[tid];
        int node = b * 256 + tid;
        int start = e0 + excl;
        cur[tid] = start;
        if (node < N) {
            rowptr[node] = start;
        }
    }
    __syncthreads();
    // rowEnd[node] = next start (cur of tid+1) or e1 for the last
    if (tid < 256) {
        int node = b * 256 + tid;
        if (node < N) rowEnd[node] = (tid < 255) ? cur[tid + 1] : e1;
    }
    __syncthreads();
    for (int i = e0 + tid; i < e1; i += 512) {
        unsigned int t = tmp[i];
        int p = atomicAdd(&cur[t & 255u], 1);
        csr[p] = (int)(t >> 8);
    }
}

// h1b[n][64](bf16) = [x[n]|topo[n]] @ W1 ; as1/ad1 from fp32 accumulators.
// Block = 64 nodes x 64 cols GEMM tile, K=136. XT fp32 + WS packed bf16 in
// LDS (52.2KB -> 3 blocks/CU). W quantized to bf16; x & acc stay fp32.
// (R27-verified config; R28's XT-bf16 regressed via unpack overhead.)
__global__ __launch_bounds__(256) void k_xform1(const float* __restrict__ x,
                                                const float* __restrict__ topo,
                                                const float* __restrict__ W1,
                                                const float* __restrict__ asrc,
                                                const float* __restrict__ adst,
                                                ushort_t* __restrict__ h1b,
                                                float* __restrict__ as1,
                                                float* __restrict__ ad1, int N) {
    __shared__ float XT[136 * 64];          // XT[k][node], fp32
    __shared__ unsigned int WSu[136 * 32];  // WS[k][c2]: bf16 pairs (17.4KB)
    int tid = threadIdx.x;
    int n0 = blockIdx.x * 64;
    {   // stage W1 packed to bf16: 2176 float4 -> 2176 uint2
        const float4* W4 = (const float4*)W1;
        for (int i = tid; i < 2176; i += 256) {
            float4 v = W4[i];
            unsigned int lo = f2bf(v.x) | (f2bf(v.y) << 16);
            unsigned int hi = f2bf(v.z) | (f2bf(v.w) << 16);
            *(uint2*)&WSu[i * 2] = make_uint2(lo, hi);
        }
    }
    {   // stage x transposed, node-minor: i = k4*64 + node
        const float4* x4 = (const float4*)x;
        for (int i = tid; i < 2048; i += 256) {
            int node = i & 63, k4 = i >> 6;
            int gn = n0 + node; if (gn > N - 1) gn = N - 1;
            float4 v = x4[(size_t)gn * 32 + k4];
            int k = k4 * 4;
            XT[(k + 0) * 64 + node] = v.x;
            XT[(k + 1) * 64 + node] = v.y;
            XT[(k + 2) * 64 + node] = v.z;
            XT[(k + 3) * 64 + node] = v.w;
        }
        // topo rows 128..135: i = j4*64 + node, j4 in {0,1}
        const float4* t4 = (const float4*)topo;
        if (tid < 128) {
            int node = tid & 63, j4 = tid >> 6;
            int gn = n0 + node; if (gn > N - 1) gn = N - 1;
            float4 v = t4[(size_t)gn * 2 + j4];
            int k = 128 + j4 * 4;
            XT[(k + 0) * 64 + node] = v.x;
            XT[(k + 1) * 64 + node] = v.y;
            XT[(k + 2) * 64 + node] = v.z;
            XT[(k + 3) * 64 + node] = v.w;
        }
    }
    __syncthreads();
    int ci = tid & 15, ni = tid >> 4;
    int nb = ni * 4, cb = ci * 4;
    float acc[16];
    #pragma unroll
    for (int i = 0; i < 16; i++) acc[i] = 0.f;
    #pragma unroll 4
    for (int k = 0; k < 136; k++) {
        float4 xv = *(const float4*)&XT[k * 64 + nb];
        uint2 wu = *(const uint2*)&WSu[k * 32 + (ci << 1)];
        float w0 = bf_lo(wu.x), w1 = bf_hi(wu.x);
        float w2 = bf_lo(wu.y), w3 = bf_hi(wu.y);
        acc[0]  = fmaf(xv.x, w0, acc[0]);  acc[1]  = fmaf(xv.x, w1, acc[1]);
        acc[2]  = fmaf(xv.x, w2, acc[2]);  acc[3]  = fmaf(xv.x, w3, acc[3]);
        acc[4]  = fmaf(xv.y, w0, acc[4]);  acc[5]  = fmaf(xv.y, w1, acc[5]);
        acc[6]  = fmaf(xv.y, w2, acc[6]);  acc[7]  = fmaf(xv.y, w3, acc[7]);
        acc[8]  = fmaf(xv.z, w0, acc[8]);  acc[9]  = fmaf(xv.z, w1, acc[9]);
        acc[10] = fmaf(xv.z, w2, acc[10]); acc[11] = fmaf(xv.z, w3, acc[11]);
        acc[12] = fmaf(xv.w, w0, acc[12]); acc[13] = fmaf(xv.w, w1, acc[13]);
        acc[14] = fmaf(xv.w, w2, acc[14]); acc[15] = fmaf(xv.w, w3, acc[15]);
    }
    int head = cb >> 3;  // cols cb..cb+3 lie in one head (cb multiple of 4)
    #pragma unroll
    for (int i = 0; i < 4; i++) {
        int n = n0 + nb + i;
        unsigned int p0 = f2bf(acc[i * 4 + 0]) | (f2bf(acc[i * 4 + 1]) << 16);
        unsigned int p1 = f2bf(acc[i * 4 + 2]) | (f2bf(acc[i * 4 + 3]) << 16);
        if (n < N) *(uint2*)&h1b[(size_t)n * 64 + cb] = make_uint2(p0, p1);
        float s = 0.f, d = 0.f;
        #pragma unroll
        for (int j = 0; j < 4; j++) {
            s = fmaf(acc[i * 4 + j], asrc[cb + j], s);
            d = fmaf(acc[i * 4 + j], adst[cb + j], d);
        }
        s += __shfl_xor(s, 1);  // combine the two half-head threads
        d += __shfl_xor(d, 1);
        if ((ci & 1) == 0 && n < N) {
            as1[n * 8 + head] = s;
            ad1[n * 8 + head] = d;
        }
    }
}

// NOTE: parameter names W_/U_ must not collide with vector members .x/.y/.z/.w
#define AGG_FMA(W_, U_)                                           \
    {                                                             \
        acc[0] = fmaf(W_, bf_lo(U_.x), acc[0]);                   \
        acc[1] = fmaf(W_, bf_hi(U_.x), acc[1]);                   \
        acc[2] = fmaf(W_, bf_lo(U_.y), acc[2]);                   \
        acc[3] = fmaf(W_, bf_hi(U_.y), acc[3]);                   \
        acc[4] = fmaf(W_, bf_lo(U_.z), acc[4]);                   \
        acc[5] = fmaf(W_, bf_hi(U_.z), acc[5]);                   \
        acc[6] = fmaf(W_, bf_lo(U_.w), acc[6]);                   \
        acc[7] = fmaf(W_, bf_hi(U_.w), acc[7]);                   \
        z += W_;                                                  \
    }

// 2-node gather: shfl within this half (nbase = nid*32); se masked to 0 when
// the half's row is empty (d==0) so no garbage-index OOB gather.
#define AGG1_GATHER(EIDX, SE_, AV_, UU_)                                     \
    int SE_ = __shfl(cv, nbase + ((EIDX) < d ? (EIDX) : dm1));               \
    SE_ = d > 0 ? SE_ : 0;                                                   \
    float AV_ = as1[SE_ * 8 + head];                                         \
    uint4 UU_ = *(const uint4*)(h1c + (((unsigned)SE_ << 7) + hoff));

#define AGG1_COMP(EIDX, AV_, UU_)                                            \
    {                                                                        \
        float w_ = (EIDX) < d ? lrelu_exp(AV_ + adv) : 0.f;                  \
        AGG_FMA(w_, UU_);                                                    \
    }

// Per-dst softmax-weighted aggregation, layer 1 (+ implicit self loop).
// R24: TWO nodes per wave. Lanes 0-31 = node A, 32-63 = node B; within a
// half: 4 edge slots x 8 heads on 128B rows. One wave-wide csr load covers
// 32 edges/node; gathers for chunks 0-5 (24 edges) issue up-front; compute
// chunks gated by wave-uniform dmax. Reduce = 2 shfl levels (xor 8/16).
__global__ __launch_bounds__(256) void k_agg1(const ushort_t* __restrict__ h1b,
                                              const float* __restrict__ as1,
                                              const float* __restrict__ ad1,
                                              const float* __restrict__ b1,
                                              const int* __restrict__ rowptr,
                                              const int* __restrict__ rowEnd,
                                              const int* __restrict__ csr,
                                              float* __restrict__ h2, int N) {
    int tid = threadIdx.x, lane = tid & 63;
    int nbase0 = blockIdx.x * 8 + ((tid >> 6) << 1);
    if (nbase0 >= N) return;              // wave-uniform
    int nid = lane >> 5;                  // node within wave (0/1)
    int nbase = nid << 5;                 // shfl base for this half
    int l32 = lane & 31;
    int g = (lane >> 3) & 3;              // edge slot 0..3
    int head = lane & 7;                  // head (cols 8h..8h+7)
    int n = nbase0 + nid;
    bool valid = n < N;
    int nc = valid ? n : N - 1;
    const char* h1c = (const char*)h1b;
    unsigned hoff = (unsigned)head << 4;  // 16B per head block
    float adv = ad1[nc * 8 + head];
    float acc[8];
    #pragma unroll
    for (int k = 0; k < 8; k++) acc[k] = 0.f;
    float z = 0.f;

    int j0 = rowptr[nc], j1 = rowEnd[nc];
    int d = valid ? (j1 - j0) : 0;
    int dm1 = d > 0 ? d - 1 : 0;
    int dx = __shfl_xor(d, 32);
    int dmax = d > dx ? d : dx;           // wave-uniform branch driver
    // ONE wave-wide csr load: 32 edges per node (value garbage if d==0;
    // address always in-bounds; masked at se stage)
    int cv = csr[j0 + (l32 < d ? l32 : dm1)];

    {   // self loop (g==0 lanes of each half: 16/64 active)
        float w = lrelu_exp(as1[nc * 8 + head] + adv);
        if (g == 0 && valid) {
            uint4 u = *(const uint4*)(h1c + (((unsigned)nc << 7) + hoff));
            acc[0] = w * bf_lo(u.x); acc[1] = w * bf_hi(u.x);
            acc[2] = w * bf_lo(u.y); acc[3] = w * bf_hi(u.y);
            acc[4] = w * bf_lo(u.z); acc[5] = w * bf_hi(u.z);
            acc[6] = w * bf_lo(u.w); acc[7] = w * bf_hi(u.w);
            z = w;
        }
    }
    if (dmax > 0) {
        // gathers for chunks 0..5 (edges 0..23 per node), 1 round trip
        int e0 = g, e1 = 4 + g, e2 = 8 + g, e3 = 12 + g, e4 = 16 + g, e5 = 20 + g;
        AGG1_GATHER(e0, s0, a0, u0)
        AGG1_GATHER(e1, s1, a1, u1)
        AGG1_GATHER(e2, s2, a2, u2)
        AGG1_GATHER(e3, s3, a3, u3)
        AGG1_GATHER(e4, s4, a4, u4)
        AGG1_GATHER(e5, s5, a5, u5)
        AGG1_COMP(e0, a0, u0)
        if (dmax > 4)  AGG1_COMP(e1, a1, u1)
        if (dmax > 8)  AGG1_COMP(e2, a2, u2)
        if (dmax > 12) AGG1_COMP(e3, a3, u3)
        if (dmax > 16) AGG1_COMP(e4, a4, u4)
        if (dmax > 20) AGG1_COMP(e5, a5, u5)
        if (dmax > 24) {                  // chunks 6/7 (edges 24..31)
            int e6 = 24 + g, e7 = 28 + g;
            AGG1_GATHER(e6, s6, a6, u6)
            AGG1_GATHER(e7, s7, a7, u7)
            AGG1_COMP(e6, a6, u6)
            if (dmax > 28) AGG1_COMP(e7, a7, u7)
            if (dmax > 32) {              // rare fallback: direct per-lane loads
                for (int eb = 32; eb < dmax; eb += 4) {
                    int e = eb + g;
                    int idx = e < d ? e : dm1;
                    int se = csr[j0 + idx];
                    se = d > 0 ? se : 0;
                    float av = as1[se * 8 + head];
                    uint4 u = *(const uint4*)(h1c + (((unsigned)se << 7) + hoff));
                    float w = e < d ? lrelu_exp(av + adv) : 0.f;
                    AGG_FMA(w, u);
                }
            }
        }
    }
    // reduce across the 4 edge-slot groups of each half (xor 8, 16 stay in-half)
    #pragma unroll
    for (int k = 0; k < 8; k++) {
        acc[k] += __shfl_xor(acc[k], 8);
        acc[k] += __shfl_xor(acc[k], 16);
    }
    z += __shfl_xor(z, 8); z += __shfl_xor(z, 16);
    if (g == 0 && valid) {
        float inv = 1.f / (z + 1e-16f);
        float o[8];
        #pragma unroll
        for (int k = 0; k < 8; k++) {
            float v = acc[k] * inv + b1[head * 8 + k];
            o[k] = v > 0.f ? v : (__expf(v) - 1.f);
        }
        float4* dp = (float4*)&h2[(size_t)n * 64 + head * 8];
        dp[0] = make_float4(o[0], o[1], o[2], o[3]);
        dp[1] = make_float4(o[4], o[5], o[6], o[7]);
    }
}

// gb[n][40](bf16) = h2[n] @ W2 ; as2/ad2 from fp32 accumulators.
// Block = 64 nodes x 40 cols GEMM tile, K=64. XT fp32 + WS packed bf16
// (R29: same verified pattern as xform1's R27). LDS 26.25 -> 21.25KB.
__global__ __launch_bounds__(256) void k_xform2(const float* __restrict__ h2,
                                                const float* __restrict__ W2,
                                                const float* __restrict__ asrc2,
                                                const float* __restrict__ adst2,
                                                ushort_t* __restrict__ gb,
                                                float* __restrict__ as2,
                                                float* __restrict__ ad2, int N) {
    __shared__ float XT[64 * 64];           // h2T[k][node]
    __shared__ unsigned int WSu[64 * 20];   // WS[k][c2]: bf16 col pairs (5.1KB)
    int tid = threadIdx.x;
    int n0 = blockIdx.x * 64;
    {   // stage W2 packed to bf16: 640 float4 -> 640 uint2
        const float4* W4 = (const float4*)W2;
        for (int i = tid; i < 640; i += 256) {
            float4 v = W4[i];
            unsigned int lo = f2bf(v.x) | (f2bf(v.y) << 16);
            unsigned int hi = f2bf(v.z) | (f2bf(v.w) << 16);
            *(uint2*)&WSu[i * 2] = make_uint2(lo, hi);
        }
    }
    {   // stage h2 transposed, node-minor: i = k4*64 + node
        const float4* h4 = (const float4*)h2;
        for (int i = tid; i < 1024; i += 256) {
            int node = i & 63, k4 = i >> 6;
            int gn = n0 + node; if (gn > N - 1) gn = N - 1;
            float4 v = h4[(size_t)gn * 16 + k4];
            int k = k4 * 4;
            XT[(k + 0) * 64 + node] = v.x;
            XT[(k + 1) * 64 + node] = v.y;
            XT[(k + 2) * 64 + node] = v.z;
            XT[(k + 3) * 64 + node] = v.w;
        }
    }
    __syncthreads();
    int ci = tid & 15, ni = tid >> 4;
    int nb = ni * 4, cb = ci * 4;
    float acc[16];
    #pragma unroll
    for (int i = 0; i < 16; i++) acc[i] = 0.f;
    if (ci < 10) {
        #pragma unroll 4
        for (int k = 0; k < 64; k++) {
            float4 xv = *(const float4*)&XT[k * 64 + nb];
            uint2 wu = *(const uint2*)&WSu[k * 20 + (ci << 1)];
            float w0 = bf_lo(wu.x), w1 = bf_hi(wu.x);
            float w2 = bf_lo(wu.y), w3 = bf_hi(wu.y);
            acc[0]  = fmaf(xv.x, w0, acc[0]);  acc[1]  = fmaf(xv.x, w1, acc[1]);
            acc[2]  = fmaf(xv.x, w2, acc[2]);  acc[3]  = fmaf(xv.x, w3, acc[3]);
            acc[4]  = fmaf(xv.y, w0, acc[4]);  acc[5]  = fmaf(xv.y, w1, acc[5]);
            acc[6]  = fmaf(xv.y, w2, acc[6]);  acc[7]  = fmaf(xv.y, w3, acc[7]);
            acc[8]  = fmaf(xv.z, w0, acc[8]);  acc[9]  = fmaf(xv.z, w1, acc[9]);
            acc[10] = fmaf(xv.z, w2, acc[10]); acc[11] = fmaf(xv.z, w3, acc[11]);
            acc[12] = fmaf(xv.w, w0, acc[12]); acc[13] = fmaf(xv.w, w1, acc[13]);
            acc[14] = fmaf(xv.w, w2, acc[14]); acc[15] = fmaf(xv.w, w3, acc[15]);
        }
    }
    #pragma unroll
    for (int i = 0; i < 4; i++) {
        int n = n0 + nb + i;
        if (ci < 10 && n < N) {
            unsigned int p0 = f2bf(acc[i * 4 + 0]) | (f2bf(acc[i * 4 + 1]) << 16);
            unsigned int p1 = f2bf(acc[i * 4 + 2]) | (f2bf(acc[i * 4 + 3]) << 16);
            *(uint2*)&gb[(size_t)n * 40 + cb] = make_uint2(p0, p1);  // 80B rows
        }
        float s = 0.f, d = 0.f;
        if (ci < 10) {
            #pragma unroll
            for (int j = 0; j < 4; j++) {
                s = fmaf(acc[i * 4 + j], asrc2[cb + j], s);
                d = fmaf(acc[i * 4 + j], adst2[cb + j], d);
            }
        }
        // reduce over the 16-lane ci group (ci>=10 contribute 0)
        s += __shfl_xor(s, 1); s += __shfl_xor(s, 2);
        s += __shfl_xor(s, 4); s += __shfl_xor(s, 8);
        d += __shfl_xor(d, 1); d += __shfl_xor(d, 2);
        d += __shfl_xor(d, 4); d += __shfl_xor(d, 8);
        if (ci == 0 && n < N) { as2[n] = s; ad2[n] = d; }
    }
}

// 2-node agg2 gather: uint2 (4 cols) of row se at this lane's col block.
// se masked to 0 when the half's row is empty (d==0).
#define AGG2_G(C_, SE_, AV_, UU_)                                            \
    int ee##C_ = 3 * (C_) + gg;                                              \
    int SE_ = __shfl(cv, nbase + (ee##C_ < d ? ee##C_ : dm1));               \
    SE_ = d > 0 ? SE_ : 0;                                                   \
    float AV_ = as2[SE_];                                                    \
    uint2 UU_ = *(const uint2*)(gbc + (unsigned)SE_ * 80u + poff);

#define AGG2_K(C_, AV_, UU_)                                                 \
    {                                                                        \
        float w_ = (ee##C_ < d) ? lrelu_exp(AV_ + add) : 0.f;                \
        acc[0] = fmaf(w_, bf_lo(UU_.x), acc[0]);                             \
        acc[1] = fmaf(w_, bf_hi(UU_.x), acc[1]);                             \
        acc[2] = fmaf(w_, bf_lo(UU_.y), acc[2]);                             \
        acc[3] = fmaf(w_, bf_hi(UU_.y), acc[3]);                             \
        z += w_;                                                             \
    }

// Layer-2 aggregation + bias + log_softmax.
// R25: TWO nodes per wave. Per half (32 lanes): 3 edge slots x 10 lanes,
// uint2 (8B = 4 cols) per lane on unpadded 80B rows; weight-lane ==
// compute-lane (each lane loads as2[se] of its own slot — no weight shfls).
// One wave-wide csr load covers 32 edges/node; gathers chunks 0..7
// (24 edges) up-front; compute gated on wave-uniform dmax; chunks 8/9 for
// dmax>24; direct-load fallback >=30. Reduce: +10/+20 shfls of ORIGINAL
// values (valid at lanes p<10 of each half). Epilogue: 4-level xor
// butterfly within each half's first 16 lanes.
__global__ __launch_bounds__(256) void k_agg2(const ushort_t* __restrict__ gb,
                                              const float* __restrict__ as2,
                                              const float* __restrict__ ad2,
                                              const float* __restrict__ b2,
                                              const int* __restrict__ rowptr,
                                              const int* __restrict__ rowEnd,
                                              const int* __restrict__ csr,
                                              float* __restrict__ out, int N) {
    int tid = threadIdx.x, lane = tid & 63;
    int nbase0 = blockIdx.x * 8 + ((tid >> 6) << 1);
    if (nbase0 >= N) return;              // wave-uniform
    int nid = lane >> 5;                  // node within wave (0/1)
    int nbase = nid << 5;                 // shfl base for this half
    int l32 = lane & 31;
    int gg = l32 / 10;                    // edge slot 0..2 (lanes 30/31 dup)
    int p = l32 - gg * 10;                // col block (4 cols each)
    if (gg > 2) { gg = 2; p = 9; }        // lanes 30,31: duplicate, unread
    int n = nbase0 + nid;
    bool valid = n < N;
    int nc = valid ? n : N - 1;
    const char* gbc = (const char*)gb;
    unsigned poff = (unsigned)p << 3;     // 8B per col block
    float add = ad2[nc];
    float acc[4] = {0.f, 0.f, 0.f, 0.f};
    float z = 0.f;

    int j0 = rowptr[nc], j1 = rowEnd[nc];
    int d = valid ? (j1 - j0) : 0;
    int dm1 = d > 0 ? d - 1 : 0;
    int dxx = __shfl_xor(d, 32);
    int dmax = d > dxx ? d : dxx;         // wave-uniform branch driver
    // ONE wave-wide csr load: 32 edges per node (masked at se stage)
    int cv = csr[j0 + (l32 < d ? l32 : dm1)];

    {   // self loop (gg==0 lanes of each half)
        float w = lrelu_exp(as2[nc] + add);
        if (gg == 0 && valid) {
            uint2 u = *(const uint2*)(gbc + (unsigned)nc * 80u + poff);
            acc[0] = w * bf_lo(u.x); acc[1] = w * bf_hi(u.x);
            acc[2] = w * bf_lo(u.y); acc[3] = w * bf_hi(u.y);
            z = w;
        }
    }
    if (dmax > 0) {
        // gathers for chunks 0..7 (edges 0..23 per node), 1 round trip
        AGG2_G(0, s0, a0, u0)
        AGG2_G(1, s1, a1, u1)
        AGG2_G(2, s2, a2, u2)
        AGG2_G(3, s3, a3, u3)
        AGG2_G(4, s4, a4, u4)
        AGG2_G(5, s5, a5, u5)
        AGG2_G(6, s6, a6, u6)
        AGG2_G(7, s7, a7, u7)
        AGG2_K(0, a0, u0)
        if (dmax > 3)  AGG2_K(1, a1, u1)
        if (dmax > 6)  AGG2_K(2, a2, u2)
        if (dmax > 9)  AGG2_K(3, a3, u3)
        if (dmax > 12) AGG2_K(4, a4, u4)
        if (dmax > 15) AGG2_K(5, a5, u5)
        if (dmax > 18) AGG2_K(6, a6, u6)
        if (dmax > 21) AGG2_K(7, a7, u7)
        if (dmax > 24) {                  // chunks 8/9 (edges 24..29)
            AGG2_G(8, s8, a8, u8)
            AGG2_G(9, s9, a9, u9)
            AGG2_K(8, a8, u8)
            if (dmax > 27) AGG2_K(9, a9, u9)
            if (dmax > 30) {              // rare fallback: direct per-lane loads
                for (int eb = 30; eb < dmax; eb += 3) {
                    int e = eb + gg;
                    int idx = e < d ? e : dm1;
                    int se = csr[j0 + idx];
                    se = d > 0 ? se : 0;
                    float av = as2[se];
                    uint2 u = *(const uint2*)(gbc + (unsigned)se * 80u + poff);
                    float w = (e < d) ? lrelu_exp(av + add) : 0.f;
                    acc[0] = fmaf(w, bf_lo(u.x), acc[0]);
                    acc[1] = fmaf(w, bf_hi(u.x), acc[1]);
                    acc[2] = fmaf(w, bf_lo(u.y), acc[2]);
                    acc[3] = fmaf(w, bf_hi(u.y), acc[3]);
                    z += w;
                }
            }
        }
    }
    // reduce across the 3 slot groups: A(p) = v(p) + v(p+10) + v(p+20).
    // Both shfls read the ORIGINAL value; result valid at lanes p<10 of
    // each half (reads stay within the half there).
    #pragma unroll
    for (int k = 0; k < 4; k++) {
        float t1 = __shfl(acc[k], lane + 10);
        float t2 = __shfl(acc[k], lane + 20);
        acc[k] += t1 + t2;
    }
    {
        float t1 = __shfl(z, lane + 10);
        float t2 = __shfl(z, lane + 20);
        z += t1 + t2;
    }
    // epilogue: lanes l32<10 hold 4 logits each (cols 4p..4p+3);
    // butterfly over each half's first 16 lanes (xor 1/2/4/8 stays inside)
    bool act = (l32 < 10) && valid;
    float l[4];
    float mv = -INFINITY;
    if (act) {
        float inv = 1.f / (z + 1e-16f);
        #pragma unroll
        for (int k = 0; k < 4; k++) {
            l[k] = acc[k] * inv + b2[p * 4 + k];
            mv = fmaxf(mv, l[k]);
        }
    }
    mv = fmaxf(mv, __shfl_xor(mv, 1));
    mv = fmaxf(mv, __shfl_xor(mv, 2));
    mv = fmaxf(mv, __shfl_xor(mv, 4));
    mv = fmaxf(mv, __shfl_xor(mv, 8));
    float ev = 0.f;
    if (act) {
        #pragma unroll
        for (int k = 0; k < 4; k++) ev += __expf(l[k] - mv);
    }
    ev += __shfl_xor(ev, 1);
    ev += __shfl_xor(ev, 2);
    ev += __shfl_xor(ev, 4);
    ev += __shfl_xor(ev, 8);
    if (act) {
        float ls = mv + __logf(ev);
        float4* dp = (float4*)&out[(size_t)n * 40 + p * 4];
        dp[0] = make_float4(l[0] - ls, l[1] - ls, l[2] - ls, l[3] - ls);
    }
}

extern "C" void kernel_launch(void* const* d_in, const int* in_sizes, int n_in,
                              void* d_out, int out_size, void* d_ws, size_t ws_size,
                              hipStream_t stream) {
    const float* x    = (const float*)d_in[0];
    const float* topo = (const float*)d_in[1];
    const int*   ei   = (const int*)d_in[2];
    const float* W1   = (const float*)d_in[3];
    const float* a_s1 = (const float*)d_in[4];
    const float* a_d1 = (const float*)d_in[5];
    const float* b1   = (const float*)d_in[6];
    const float* W2   = (const float*)d_in[7];
    const float* a_s2 = (const float*)d_in[8];
    const float* a_d2 = (const float*)d_in[9];
    const float* b2   = (const float*)d_in[10];
    float* out = (float*)d_out;

    int N = in_sizes[0] / 128;
    int E = in_sizes[2] / 2;
    const int* esrc = ei;
    const int* edst = ei + E;
    int NBUK = (N + 255) / 256;
    size_t cap = (size_t)NBUK * BUK_CAP;

    char* ws = (char*)d_ws;
    size_t off = 0;
    auto alloc = [&](size_t bytes) -> void* {
        void* p = ws + off;
        off = (off + bytes + 255) & ~(size_t)255;
        return p;
    };
    ushort_t* h1b  = (ushort_t*)alloc((size_t)N * 64 * 2);
    float* as1     = (float*)alloc((size_t)N * 8 * 4);
    float* ad1     = (float*)alloc((size_t)N * 8 * 4);
    float* h2      = (float*)alloc((size_t)N * 64 * 4);
    ushort_t* gb   = (ushort_t*)alloc((size_t)N * 40 * 2);  // 80B rows
    float* as2     = (float*)alloc((size_t)N * 4);
    float* ad2     = (float*)alloc((size_t)N * 4);
    int*   rowptr  = (int*)alloc((size_t)N * 4);
    int*   rowEnd  = (int*)alloc((size_t)N * 4);
    int*   csr     = (int*)alloc(cap * 4);
    unsigned int* tmp = (unsigned int*)alloc(cap * 4);
    int* gCursor   = (int*)alloc((size_t)NBUK * 4);

    hipMemsetAsync(gCursor, 0, (size_t)NBUK * 4, stream);  // count-based cursors
    int nbin = (E + BIN_CHUNK - 1) / BIN_CHUNK;
    k_bin<<<nbin, 256, 0, stream>>>(esrc, edst, gCursor, tmp, E, NBUK);
    k_fill2<<<NBUK, 512, 0, stream>>>(tmp, gCursor, rowptr, rowEnd, csr, N);

    int nbg = (N + 63) / 64;  // 64-node GEMM tiles
    int nb8 = (N + 7) / 8;    // 2 nodes/wave x 4 waves/block (agg kernels)
    k_xform1<<<nbg, 256, 0, stream>>>(x, topo, W1, a_s1, a_d1, h1b, as1, ad1, N);
    k_agg1<<<nb8, 256, 0, stream>>>(h1b, as1, ad1, b1, rowptr, rowEnd, csr, h2, N);
    k_xform2<<<nbg, 256, 0, stream>>>(h2, W2, a_s2, a_d2, gb, as2, ad2, N);
    k_agg2<<<nb8, 256, 0, stream>>>(gb, as2, ad2, b2, rowptr, rowEnd, csr, out, N);
}

// Round 16
// 271.447 us; speedup vs baseline: 1.0468x; 1.0468x over previous
//
#include <hip/hip_runtime.h>
#include <math.h>

// ---------------------------------------------------------------------------
// TopoGAT: 2-layer GAT on MI355X.
// R10: fixed-capacity bucket CSR build; padded CSR with rowptr/rowEnd.
// R5:  gather tables h1/g in bf16.
// R14: CSR build — k_bin BIN_CHUNK=4096; k_fill2 512thr + uint4 count pass.
// R21/R22: agg kernels -> 1 wave-wide csr load + all gathers up-front.
// R24/R25: agg kernels -> 2 nodes/wave: agg1 ~48.5, agg2 <48. VERIFIED.
// R26 FAILED: W1-from-global (34.8KB > 32KB L1). R27: WS bf16 in LDS ->
//      xform1 ~49.5 VERIFIED BEST scalar. R28 FAILED: XT bf16 (unpack VALU
//      ate occupancy gain). R29 NEUTRAL/NEG: xform2-bf16 (already 6
//      blocks/CU -> unpacks w/o occupancy payoff); also measured agg1
//      run-noise ~±2us. LESSON: W-bf16-LDS pays only when blocks/CU rises.
// R30: k_xform1 -> MFMA (mfma_f32_16x16x32_bf16). Numerics pre-validated:
//      R28 ran full-bf16 inputs with absmax unchanged 0.03125. Both
//      operands bf16 LDS [64][168] (K 136->160 zero-pad; 168 row-pitch
//      avoids 8-way bank conflicts). 4 waves x 4 n-tiles; 5 Ksteps x
//      (5 ds_read_b128 + 4 MFMA) = 20 MFMA/wave replaces 136-iter FMA
//      loop. LDS 43KB -> 3 blocks/CU. C layout (HW-verified in guide):
//      col=lane&15, row=(lane>>4)*4+reg. A: row=l&15,kblk=l>>4; B:
//      col=l&15,kblk=l>>4 (canonical; absmax will catch a swap).
//      xform2 REVERTED to R13 fp32-WS.
// ---------------------------------------------------------------------------

#define NBUK_MAX 512
#define BIN_CHUNK 4096
#define BUK_CAP 4608

typedef unsigned short ushort_t;
typedef short bf16x8 __attribute__((ext_vector_type(8)));
typedef float f32x4 __attribute__((ext_vector_type(4)));

__device__ inline unsigned int f2bf(float f) {  // RNE fp32->bf16
    unsigned int u = __float_as_uint(f);
    u += 0x7FFFu + ((u >> 16) & 1u);
    return u >> 16;
}
__device__ inline float bf_lo(unsigned int u) {
    return __uint_as_float(u << 16);
}
__device__ inline float bf_hi(unsigned int u) {
    return __uint_as_float(u & 0xFFFF0000u);
}
__device__ inline float lrelu_exp(float q) {
    return __expf(q >= 0.f ? q : 0.2f * q);
}

__device__ inline int wave_incl_scan(int v, int lane) {
    #pragma unroll
    for (int ofs = 1; ofs < 64; ofs <<= 1) {
        int t = __shfl_up(v, ofs);
        if (lane >= ofs) v += t;
    }
    return v;
}

// Bin edges into fixed-capacity bucket regions of tmp. One global atomic per
// (block,bucket); packed word = (src<<8) | (dst&255). 16 edges/thread via
// int4 loads; dst stashed in registers across the reservation barrier.
__global__ __launch_bounds__(256) void k_bin(const int* __restrict__ src,
                                             const int* __restrict__ dst,
                                             int* __restrict__ gCursor,
                                             unsigned int* __restrict__ tmp,
                                             int E, int NBUK) {
    __shared__ int lcnt[NBUK_MAX];
    __shared__ int lcur[NBUK_MAX];
    int tid = threadIdx.x;
    int base = blockIdx.x * BIN_CHUNK;
    for (int i = tid; i < NBUK; i += 256) lcnt[i] = 0;
    __syncthreads();
    int d[16];
    #pragma unroll
    for (int q = 0; q < 4; q++) {
        int e = base + q * 1024 + 4 * tid;
        if (e + 3 < E) {
            int4 v = *(const int4*)&dst[e];
            d[4 * q + 0] = v.x; d[4 * q + 1] = v.y;
            d[4 * q + 2] = v.z; d[4 * q + 3] = v.w;
        } else {
            #pragma unroll
            for (int k = 0; k < 4; k++)
                d[4 * q + k] = (e + k < E) ? dst[e + k] : -1;
        }
    }
    #pragma unroll
    for (int k = 0; k < 16; k++)
        if (d[k] >= 0) atomicAdd(&lcnt[d[k] >> 8], 1);
    __syncthreads();
    for (int b = tid; b < NBUK; b += 256) {
        int c = lcnt[b];
        lcur[b] = c ? b * BUK_CAP + atomicAdd(&gCursor[b], c) : 0;
    }
    __syncthreads();
    #pragma unroll
    for (int q = 0; q < 4; q++) {
        int e = base + q * 1024 + 4 * tid;
        int s[4];
        if (e + 3 < E) {
            int4 v = *(const int4*)&src[e];
            s[0] = v.x; s[1] = v.y; s[2] = v.z; s[3] = v.w;
        } else {
            #pragma unroll
            for (int k = 0; k < 4; k++)
                s[k] = (e + k < E) ? src[e + k] : 0;
        }
        #pragma unroll
        for (int k = 0; k < 4; k++) {
            int dd = d[4 * q + k];
            if (dd >= 0) {
                int p = atomicAdd(&lcur[dd >> 8], 1);
                tmp[p] = ((unsigned int)s[k] << 8) | (unsigned int)(dd & 255);
            }
        }
    }
}

// Exact CSR fill within a bucket (padded layout, base = b*BUK_CAP).
// 512 threads; count pass reads tmp as uint4.
__global__ __launch_bounds__(512) void k_fill2(const unsigned int* __restrict__ tmp,
                                               const int* __restrict__ gCursor,
                                               int* __restrict__ rowptr,
                                               int* __restrict__ rowEnd,
                                               int* __restrict__ csr, int N) {
    __shared__ int cnt[256];
    __shared__ int cur[256];
    __shared__ int wsum[4];
    int b = blockIdx.x, tid = threadIdx.x;
    int e0 = b * BUK_CAP;
    int cnt_e = gCursor[b];       // bucket edge count
    int e1 = e0 + cnt_e;
    if (tid < 256) cnt[tid] = 0;
    __syncthreads();
    {   // count pass: uint4 over the bulk (e0 is 16B-aligned: BUK_CAP*4 % 16 == 0)
        int nq = cnt_e >> 2;
        const uint4* t4 = (const uint4*)(tmp + e0);
        for (int q = tid; q < nq; q += 512) {
            uint4 v = t4[q];
            atomicAdd(&cnt[v.x & 255u], 1);
            atomicAdd(&cnt[v.y & 255u], 1);
            atomicAdd(&cnt[v.z & 255u], 1);
            atomicAdd(&cnt[v.w & 255u], 1);
        }
        for (int i = (nq << 2) + tid; i < cnt_e; i += 512)
            atomicAdd(&cnt[tmp[e0 + i] & 255u], 1);
    }
    __syncthreads();
    if (tid < 256) {
        int lane = tid & 63, wv = tid >> 6;
        int v = cnt[tid];
        int incl = wave_incl_scan(v, lane);
        if (lane == 63) wsum[wv] = incl;
        cnt[tid] = incl - v;  // stash exclusive-within-wave
    }
    __syncthreads();
    if (tid < 256) {
        int wv = tid >> 6;
        int woff = 0;
        for (int i = 0; i < wv; i++) woff += wsum[i];
        int excl = woff + cnt[tid];
        int node = b * 256 + tid;
        int start = e0 + excl;
        cur[tid] = start;
        if (node < N) {
            rowptr[node] = start;
        }
    }
    __syncthreads();
    // rowEnd[node] = next start (cur of tid+1) or e1 for the last
    if (tid < 256) {
        int node = b * 256 + tid;
        if (node < N) rowEnd[node] = (tid < 255) ? cur[tid + 1] : e1;
    }
    __syncthreads();
    for (int i = e0 + tid; i < e1; i += 512) {
        unsigned int t = tmp[i];
        int p = atomicAdd(&cur[t & 255u], 1);
        csr[p] = (int)(t >> 8);
    }
}

// h1b[n][64](bf16) = [x[n]|topo[n]] @ W1 via MFMA; as1/ad1 from C-frags.
// Block = 64 nodes x 64 cols, K=136 zero-padded to 160. A=[node][k] bf16,
// B=W1^T=[col][k] bf16 in LDS (pitch 168 -> 2-way-free reads; 43KB total).
// 4 waves: wave w owns rows 16w..16w+15, computes 4 col-tiles.
__global__ __launch_bounds__(256) void k_xform1(const float* __restrict__ x,
                                                const float* __restrict__ topo,
                                                const float* __restrict__ W1,
                                                const float* __restrict__ asrc,
                                                const float* __restrict__ adst,
                                                ushort_t* __restrict__ h1b,
                                                float* __restrict__ as1,
                                                float* __restrict__ ad1, int N) {
    __shared__ ushort_t XA[64 * 168];  // [node][k] bf16 (21.5KB)
    __shared__ ushort_t WB[64 * 168];  // [col][k]  bf16 (21.5KB)
    unsigned int* XAu = (unsigned int*)XA;
    unsigned int* WBu = (unsigned int*)WB;
    int tid = threadIdx.x;
    int n0 = blockIdx.x * 64;
    // stage x (k 0..127) as bf16 pairs, row-major per node
    const float4* x4 = (const float4*)x;
    for (int i = tid; i < 2048; i += 256) {
        int nd = i >> 5, q = i & 31;
        int gn = n0 + nd; if (gn > N - 1) gn = N - 1;
        float4 v = x4[(size_t)gn * 32 + q];
        XAu[nd * 84 + 2 * q]     = f2bf(v.x) | (f2bf(v.y) << 16);
        XAu[nd * 84 + 2 * q + 1] = f2bf(v.z) | (f2bf(v.w) << 16);
    }
    // topo (k 128..135)
    const float4* t4 = (const float4*)topo;
    for (int i = tid; i < 128; i += 256) {
        int nd = i >> 1, q = i & 1;
        int gn = n0 + nd; if (gn > N - 1) gn = N - 1;
        float4 v = t4[(size_t)gn * 2 + q];
        XAu[nd * 84 + 64 + 2 * q]     = f2bf(v.x) | (f2bf(v.y) << 16);
        XAu[nd * 84 + 64 + 2 * q + 1] = f2bf(v.z) | (f2bf(v.w) << 16);
    }
    // zero pad k 136..167
    for (int i = tid; i < 1024; i += 256) {
        int nd = i >> 4, q = i & 15;
        XAu[nd * 84 + 68 + q] = 0;
    }
    // stage W1 transposed: WB[c][k] = W1[k][c] (coalesced over c)
    {
        int c = tid & 63;
        for (int k = tid >> 6; k < 136; k += 4)
            WB[c * 168 + k] = (ushort_t)f2bf(W1[k * 64 + c]);
    }
    for (int i = tid; i < 1024; i += 256) {
        int c = i >> 4, q = i & 15;
        WBu[c * 84 + 68 + q] = 0;
    }
    __syncthreads();
    int w = tid >> 6, l = tid & 63;
    int cl = l & 15;
    int arow = (w << 4) + cl;          // A-frag row (node within block)
    int kb0 = (l >> 4) << 3;           // lane k-base within a 32-K step
    f32x4 acc0 = {0.f, 0.f, 0.f, 0.f};
    f32x4 acc1 = acc0, acc2 = acc0, acc3 = acc0;
    #pragma unroll
    for (int ks = 0; ks < 5; ks++) {
        int kb = kb0 + (ks << 5);
        bf16x8 af = *(const bf16x8*)&XA[arow * 168 + kb];
        bf16x8 b0 = *(const bf16x8*)&WB[(cl)      * 168 + kb];
        bf16x8 b1 = *(const bf16x8*)&WB[(16 + cl) * 168 + kb];
        bf16x8 b2 = *(const bf16x8*)&WB[(32 + cl) * 168 + kb];
        bf16x8 b3 = *(const bf16x8*)&WB[(48 + cl) * 168 + kb];
        acc0 = __builtin_amdgcn_mfma_f32_16x16x32_bf16(af, b0, acc0, 0, 0, 0);
        acc1 = __builtin_amdgcn_mfma_f32_16x16x32_bf16(af, b1, acc1, 0, 0, 0);
        acc2 = __builtin_amdgcn_mfma_f32_16x16x32_bf16(af, b2, acc2, 0, 0, 0);
        acc3 = __builtin_amdgcn_mfma_f32_16x16x32_bf16(af, b3, acc3, 0, 0, 0);
    }
    // epilogue: C layout col=l&15 (per tile), row=(l>>4)*4+reg (HW-verified)
    int rbase = n0 + (w << 4) + ((l >> 4) << 2);
    #pragma unroll
    for (int nt = 0; nt < 4; nt++) {
        f32x4 a = (nt == 0) ? acc0 : (nt == 1) ? acc1 : (nt == 2) ? acc2 : acc3;
        int col = (nt << 4) + cl;
        float asc = asrc[col], adc = adst[col];
        #pragma unroll
        for (int r = 0; r < 4; r++) {
            int n = rbase + r;
            if (n < N) h1b[(size_t)n * 64 + col] = (ushort_t)f2bf(a[r]);
            float s = a[r] * asc;
            float dd = a[r] * adc;
            s += __shfl_xor(s, 1); s += __shfl_xor(s, 2); s += __shfl_xor(s, 4);
            dd += __shfl_xor(dd, 1); dd += __shfl_xor(dd, 2); dd += __shfl_xor(dd, 4);
            if ((l & 7) == 0 && n < N) {
                int head = col >> 3;
                as1[n * 8 + head] = s;
                ad1[n * 8 + head] = dd;
            }
        }
    }
}

// NOTE: parameter names W_/U_ must not collide with vector members .x/.y/.z/.w
#define AGG_FMA(W_, U_)                                           \
    {                                                             \
        acc[0] = fmaf(W_, bf_lo(U_.x), acc[0]);                   \
        acc[1] = fmaf(W_, bf_hi(U_.x), acc[1]);                   \
        acc[2] = fmaf(W_, bf_lo(U_.y), acc[2]);                   \
        acc[3] = fmaf(W_, bf_hi(U_.y), acc[3]);                   \
        acc[4] = fmaf(W_, bf_lo(U_.z), acc[4]);                   \
        acc[5] = fmaf(W_, bf_hi(U_.z), acc[5]);                   \
        acc[6] = fmaf(W_, bf_lo(U_.w), acc[6]);                   \
        acc[7] = fmaf(W_, bf_hi(U_.w), acc[7]);                   \
        z += W_;                                                  \
    }

// 2-node gather: shfl within this half (nbase = nid*32); se masked to 0 when
// the half's row is empty (d==0) so no garbage-index OOB gather.
#define AGG1_GATHER(EIDX, SE_, AV_, UU_)                                     \
    int SE_ = __shfl(cv, nbase + ((EIDX) < d ? (EIDX) : dm1));               \
    SE_ = d > 0 ? SE_ : 0;                                                   \
    float AV_ = as1[SE_ * 8 + head];                                         \
    uint4 UU_ = *(const uint4*)(h1c + (((unsigned)SE_ << 7) + hoff));

#define AGG1_COMP(EIDX, AV_, UU_)                                            \
    {                                                                        \
        float w_ = (EIDX) < d ? lrelu_exp(AV_ + adv) : 0.f;                  \
        AGG_FMA(w_, UU_);                                                    \
    }

// Per-dst softmax-weighted aggregation, layer 1 (+ implicit self loop).
// R24: TWO nodes per wave. Lanes 0-31 = node A, 32-63 = node B; within a
// half: 4 edge slots x 8 heads on 128B rows. One wave-wide csr load covers
// 32 edges/node; gathers for chunks 0-5 (24 edges) issue up-front; compute
// chunks gated by wave-uniform dmax. Reduce = 2 shfl levels (xor 8/16).
__global__ __launch_bounds__(256) void k_agg1(const ushort_t* __restrict__ h1b,
                                              const float* __restrict__ as1,
                                              const float* __restrict__ ad1,
                                              const float* __restrict__ b1,
                                              const int* __restrict__ rowptr,
                                              const int* __restrict__ rowEnd,
                                              const int* __restrict__ csr,
                                              float* __restrict__ h2, int N) {
    int tid = threadIdx.x, lane = tid & 63;
    int nbase0 = blockIdx.x * 8 + ((tid >> 6) << 1);
    if (nbase0 >= N) return;              // wave-uniform
    int nid = lane >> 5;                  // node within wave (0/1)
    int nbase = nid << 5;                 // shfl base for this half
    int l32 = lane & 31;
    int g = (lane >> 3) & 3;              // edge slot 0..3
    int head = lane & 7;                  // head (cols 8h..8h+7)
    int n = nbase0 + nid;
    bool valid = n < N;
    int nc = valid ? n : N - 1;
    const char* h1c = (const char*)h1b;
    unsigned hoff = (unsigned)head << 4;  // 16B per head block
    float adv = ad1[nc * 8 + head];
    float acc[8];
    #pragma unroll
    for (int k = 0; k < 8; k++) acc[k] = 0.f;
    float z = 0.f;

    int j0 = rowptr[nc], j1 = rowEnd[nc];
    int d = valid ? (j1 - j0) : 0;
    int dm1 = d > 0 ? d - 1 : 0;
    int dx = __shfl_xor(d, 32);
    int dmax = d > dx ? d : dx;           // wave-uniform branch driver
    // ONE wave-wide csr load: 32 edges per node (value garbage if d==0;
    // address always in-bounds; masked at se stage)
    int cv = csr[j0 + (l32 < d ? l32 : dm1)];

    {   // self loop (g==0 lanes of each half: 16/64 active)
        float w = lrelu_exp(as1[nc * 8 + head] + adv);
        if (g == 0 && valid) {
            uint4 u = *(const uint4*)(h1c + (((unsigned)nc << 7) + hoff));
            acc[0] = w * bf_lo(u.x); acc[1] = w * bf_hi(u.x);
            acc[2] = w * bf_lo(u.y); acc[3] = w * bf_hi(u.y);
            acc[4] = w * bf_lo(u.z); acc[5] = w * bf_hi(u.z);
            acc[6] = w * bf_lo(u.w); acc[7] = w * bf_hi(u.w);
            z = w;
        }
    }
    if (dmax > 0) {
        // gathers for chunks 0..5 (edges 0..23 per node), 1 round trip
        int e0 = g, e1 = 4 + g, e2 = 8 + g, e3 = 12 + g, e4 = 16 + g, e5 = 20 + g;
        AGG1_GATHER(e0, s0, a0, u0)
        AGG1_GATHER(e1, s1, a1, u1)
        AGG1_GATHER(e2, s2, a2, u2)
        AGG1_GATHER(e3, s3, a3, u3)
        AGG1_GATHER(e4, s4, a4, u4)
        AGG1_GATHER(e5, s5, a5, u5)
        AGG1_COMP(e0, a0, u0)
        if (dmax > 4)  AGG1_COMP(e1, a1, u1)
        if (dmax > 8)  AGG1_COMP(e2, a2, u2)
        if (dmax > 12) AGG1_COMP(e3, a3, u3)
        if (dmax > 16) AGG1_COMP(e4, a4, u4)
        if (dmax > 20) AGG1_COMP(e5, a5, u5)
        if (dmax > 24) {                  // chunks 6/7 (edges 24..31)
            int e6 = 24 + g, e7 = 28 + g;
            AGG1_GATHER(e6, s6, a6, u6)
            AGG1_GATHER(e7, s7, a7, u7)
            AGG1_COMP(e6, a6, u6)
            if (dmax > 28) AGG1_COMP(e7, a7, u7)
            if (dmax > 32) {              // rare fallback: direct per-lane loads
                for (int eb = 32; eb < dmax; eb += 4) {
                    int e = eb + g;
                    int idx = e < d ? e : dm1;
                    int se = csr[j0 + idx];
                    se = d > 0 ? se : 0;
                    float av = as1[se * 8 + head];
                    uint4 u = *(const uint4*)(h1c + (((unsigned)se << 7) + hoff));
                    float w = e < d ? lrelu_exp(av + adv) : 0.f;
                    AGG_FMA(w, u);
                }
            }
        }
    }
    // reduce across the 4 edge-slot groups of each half (xor 8, 16 stay in-half)
    #pragma unroll
    for (int k = 0; k < 8; k++) {
        acc[k] += __shfl_xor(acc[k], 8);
        acc[k] += __shfl_xor(acc[k], 16);
    }
    z += __shfl_xor(z, 8); z += __shfl_xor(z, 16);
    if (g == 0 && valid) {
        float inv = 1.f / (z + 1e-16f);
        float o[8];
        #pragma unroll
        for (int k = 0; k < 8; k++) {
            float v = acc[k] * inv + b1[head * 8 + k];
            o[k] = v > 0.f ? v : (__expf(v) - 1.f);
        }
        float4* dp = (float4*)&h2[(size_t)n * 64 + head * 8];
        dp[0] = make_float4(o[0], o[1], o[2], o[3]);
        dp[1] = make_float4(o[4], o[5], o[6], o[7]);
    }
}

// gb[n][40](bf16) = h2[n] @ W2 ; as2/ad2 from fp32 accumulators.
// Block = 64 nodes x 40 cols GEMM tile, K=64. Node-minor staging.
// (R13-verified fp32-WS config; R29's WS-bf16 reverted — xform2 is not
// occupancy-limited, so unpacks were pure VALU cost.)
__global__ __launch_bounds__(256) void k_xform2(const float* __restrict__ h2,
                                                const float* __restrict__ W2,
                                                const float* __restrict__ asrc2,
                                                const float* __restrict__ adst2,
                                                ushort_t* __restrict__ gb,
                                                float* __restrict__ as2,
                                                float* __restrict__ ad2, int N) {
    __shared__ float XT[64 * 64];  // h2T[k][node]
    __shared__ float WS[64 * 40];  // WS[k][col]
    int tid = threadIdx.x;
    int n0 = blockIdx.x * 64;
    {   // stage W2: 2560 floats = 640 float4
        const float4* W4 = (const float4*)W2;
        float4* WS4 = (float4*)WS;
        for (int i = tid; i < 640; i += 256) WS4[i] = W4[i];
    }
    {   // stage h2 transposed, node-minor: i = k4*64 + node
        const float4* h4 = (const float4*)h2;
        for (int i = tid; i < 1024; i += 256) {
            int node = i & 63, k4 = i >> 6;
            int gn = n0 + node; if (gn > N - 1) gn = N - 1;
            float4 v = h4[(size_t)gn * 16 + k4];
            int k = k4 * 4;
            XT[(k + 0) * 64 + node] = v.x;
            XT[(k + 1) * 64 + node] = v.y;
            XT[(k + 2) * 64 + node] = v.z;
            XT[(k + 3) * 64 + node] = v.w;
        }
    }
    __syncthreads();
    int ci = tid & 15, ni = tid >> 4;
    int nb = ni * 4, cb = ci * 4;
    float acc[16];
    #pragma unroll
    for (int i = 0; i < 16; i++) acc[i] = 0.f;
    if (ci < 10) {
        #pragma unroll 4
        for (int k = 0; k < 64; k++) {
            float4 xv = *(const float4*)&XT[k * 64 + nb];
            float4 wv = *(const float4*)&WS[k * 40 + cb];
            acc[0]  = fmaf(xv.x, wv.x, acc[0]);  acc[1]  = fmaf(xv.x, wv.y, acc[1]);
            acc[2]  = fmaf(xv.x, wv.z, acc[2]);  acc[3]  = fmaf(xv.x, wv.w, acc[3]);
            acc[4]  = fmaf(xv.y, wv.x, acc[4]);  acc[5]  = fmaf(xv.y, wv.y, acc[5]);
            acc[6]  = fmaf(xv.y, wv.z, acc[6]);  acc[7]  = fmaf(xv.y, wv.w, acc[7]);
            acc[8]  = fmaf(xv.z, wv.x, acc[8]);  acc[9]  = fmaf(xv.z, wv.y, acc[9]);
            acc[10] = fmaf(xv.z, wv.z, acc[10]); acc[11] = fmaf(xv.z, wv.w, acc[11]);
            acc[12] = fmaf(xv.w, wv.x, acc[12]); acc[13] = fmaf(xv.w, wv.y, acc[13]);
            acc[14] = fmaf(xv.w, wv.z, acc[14]); acc[15] = fmaf(xv.w, wv.w, acc[15]);
        }
    }
    #pragma unroll
    for (int i = 0; i < 4; i++) {
        int n = n0 + nb + i;
        if (ci < 10 && n < N) {
            unsigned int p0 = f2bf(acc[i * 4 + 0]) | (f2bf(acc[i * 4 + 1]) << 16);
            unsigned int p1 = f2bf(acc[i * 4 + 2]) | (f2bf(acc[i * 4 + 3]) << 16);
            *(uint2*)&gb[(size_t)n * 40 + cb] = make_uint2(p0, p1);  // 80B rows
        }
        float s = 0.f, d = 0.f;
        if (ci < 10) {
            #pragma unroll
            for (int j = 0; j < 4; j++) {
                s = fmaf(acc[i * 4 + j], asrc2[cb + j], s);
                d = fmaf(acc[i * 4 + j], adst2[cb + j], d);
            }
        }
        // reduce over the 16-lane ci group (ci>=10 contribute 0)
        s += __shfl_xor(s, 1); s += __shfl_xor(s, 2);
        s += __shfl_xor(s, 4); s += __shfl_xor(s, 8);
        d += __shfl_xor(d, 1); d += __shfl_xor(d, 2);
        d += __shfl_xor(d, 4); d += __shfl_xor(d, 8);
        if (ci == 0 && n < N) { as2[n] = s; ad2[n] = d; }
    }
}

// 2-node agg2 gather: uint2 (4 cols) of row se at this lane's col block.
// se masked to 0 when the half's row is empty (d==0).
#define AGG2_G(C_, SE_, AV_, UU_)                                            \
    int ee##C_ = 3 * (C_) + gg;                                              \
    int SE_ = __shfl(cv, nbase + (ee##C_ < d ? ee##C_ : dm1));               \
    SE_ = d > 0 ? SE_ : 0;                                                   \
    float AV_ = as2[SE_];                                                    \
    uint2 UU_ = *(const uint2*)(gbc + (unsigned)SE_ * 80u + poff);

#define AGG2_K(C_, AV_, UU_)                                                 \
    {                                                                        \
        float w_ = (ee##C_ < d) ? lrelu_exp(AV_ + add) : 0.f;                \
        acc[0] = fmaf(w_, bf_lo(UU_.x), acc[0]);                             \
        acc[1] = fmaf(w_, bf_hi(UU_.x), acc[1]);                             \
        acc[2] = fmaf(w_, bf_lo(UU_.y), acc[2]);                             \
        acc[3] = fmaf(w_, bf_hi(UU_.y), acc[3]);                             \
        z += w_;                                                             \
    }

// Layer-2 aggregation + bias + log_softmax.
// R25: TWO nodes per wave. Per half (32 lanes): 3 edge slots x 10 lanes,
// uint2 (8B = 4 cols) per lane on unpadded 80B rows; weight-lane ==
// compute-lane (each lane loads as2[se] of its own slot — no weight shfls).
// One wave-wide csr load covers 32 edges/node; gathers chunks 0..7
// (24 edges) up-front; compute gated on wave-uniform dmax; chunks 8/9 for
// dmax>24; direct-load fallback >=30. Reduce: +10/+20 shfls of ORIGINAL
// values (valid at lanes p<10 of each half). Epilogue: 4-level xor
// butterfly within each half's first 16 lanes.
__global__ __launch_bounds__(256) void k_agg2(const ushort_t* __restrict__ gb,
                                              const float* __restrict__ as2,
                                              const float* __restrict__ ad2,
                                              const float* __restrict__ b2,
                                              const int* __restrict__ rowptr,
                                              const int* __restrict__ rowEnd,
                                              const int* __restrict__ csr,
                                              float* __restrict__ out, int N) {
    int tid = threadIdx.x, lane = tid & 63;
    int nbase0 = blockIdx.x * 8 + ((tid >> 6) << 1);
    if (nbase0 >= N) return;              // wave-uniform
    int nid = lane >> 5;                  // node within wave (0/1)
    int nbase = nid << 5;                 // shfl base for this half
    int l32 = lane & 31;
    int gg = l32 / 10;                    // edge slot 0..2 (lanes 30/31 dup)
    int p = l32 - gg * 10;                // col block (4 cols each)
    if (gg > 2) { gg = 2; p = 9; }        // lanes 30,31: duplicate, unread
    int n = nbase0 + nid;
    bool valid = n < N;
    int nc = valid ? n : N - 1;
    const char* gbc = (const char*)gb;
    unsigned poff = (unsigned)p << 3;     // 8B per col block
    float add = ad2[nc];
    float acc[4] = {0.f, 0.f, 0.f, 0.f};
    float z = 0.f;

    int j0 = rowptr[nc], j1 = rowEnd[nc];
    int d = valid ? (j1 - j0) : 0;
    int dm1 = d > 0 ? d - 1 : 0;
    int dxx = __shfl_xor(d, 32);
    int dmax = d > dxx ? d : dxx;         // wave-uniform branch driver
    // ONE wave-wide csr load: 32 edges per node (masked at se stage)
    int cv = csr[j0 + (l32 < d ? l32 : dm1)];

    {   // self loop (gg==0 lanes of each half)
        float w = lrelu_exp(as2[nc] + add);
        if (gg == 0 && valid) {
            uint2 u = *(const uint2*)(gbc + (unsigned)nc * 80u + poff);
            acc[0] = w * bf_lo(u.x); acc[1] = w * bf_hi(u.x);
            acc[2] = w * bf_lo(u.y); acc[3] = w * bf_hi(u.y);
            z = w;
        }
    }
    if (dmax > 0) {
        // gathers for chunks 0..7 (edges 0..23 per node), 1 round trip
        AGG2_G(0, s0, a0, u0)
        AGG2_G(1, s1, a1, u1)
        AGG2_G(2, s2, a2, u2)
        AGG2_G(3, s3, a3, u3)
        AGG2_G(4, s4, a4, u4)
        AGG2_G(5, s5, a5, u5)
        AGG2_G(6, s6, a6, u6)
        AGG2_G(7, s7, a7, u7)
        AGG2_K(0, a0, u0)
        if (dmax > 3)  AGG2_K(1, a1, u1)
        if (dmax > 6)  AGG2_K(2, a2, u2)
        if (dmax > 9)  AGG2_K(3, a3, u3)
        if (dmax > 12) AGG2_K(4, a4, u4)
        if (dmax > 15) AGG2_K(5, a5, u5)
        if (dmax > 18) AGG2_K(6, a6, u6)
        if (dmax > 21) AGG2_K(7, a7, u7)
        if (dmax > 24) {                  // chunks 8/9 (edges 24..29)
            AGG2_G(8, s8, a8, u8)
            AGG2_G(9, s9, a9, u9)
            AGG2_K(8, a8, u8)
            if (dmax > 27) AGG2_K(9, a9, u9)
            if (dmax > 30) {              // rare fallback: direct per-lane loads
                for (int eb = 30; eb < dmax; eb += 3) {
                    int e = eb + gg;
                    int idx = e < d ? e : dm1;
                    int se = csr[j0 + idx];
                    se = d > 0 ? se : 0;
                    float av = as2[se];
                    uint2 u = *(const uint2*)(gbc + (unsigned)se * 80u + poff);
                    float w = (e < d) ? lrelu_exp(av + add) : 0.f;
                    acc[0] = fmaf(w, bf_lo(u.x), acc[0]);
                    acc[1] = fmaf(w, bf_hi(u.x), acc[1]);
                    acc[2] = fmaf(w, bf_lo(u.y), acc[2]);
                    acc[3] = fmaf(w, bf_hi(u.y), acc[3]);
                    z += w;
                }
            }
        }
    }
    // reduce across the 3 slot groups: A(p) = v(p) + v(p+10) + v(p+20).
    // Both shfls read the ORIGINAL value; result valid at lanes p<10 of
    // each half (reads stay within the half there).
    #pragma unroll
    for (int k = 0; k < 4; k++) {
        float t1 = __shfl(acc[k], lane + 10);
        float t2 = __shfl(acc[k], lane + 20);
        acc[k] += t1 + t2;
    }
    {
        float t1 = __shfl(z, lane + 10);
        float t2 = __shfl(z, lane + 20);
        z += t1 + t2;
    }
    // epilogue: lanes l32<10 hold 4 logits each (cols 4p..4p+3);
    // butterfly over each half's first 16 lanes (xor 1/2/4/8 stays inside)
    bool act = (l32 < 10) && valid;
    float l[4];
    float mv = -INFINITY;
    if (act) {
        float inv = 1.f / (z + 1e-16f);
        #pragma unroll
        for (int k = 0; k < 4; k++) {
            l[k] = acc[k] * inv + b2[p * 4 + k];
            mv = fmaxf(mv, l[k]);
        }
    }
    mv = fmaxf(mv, __shfl_xor(mv, 1));
    mv = fmaxf(mv, __shfl_xor(mv, 2));
    mv = fmaxf(mv, __shfl_xor(mv, 4));
    mv = fmaxf(mv, __shfl_xor(mv, 8));
    float ev = 0.f;
    if (act) {
        #pragma unroll
        for (int k = 0; k < 4; k++) ev += __expf(l[k] - mv);
    }
    ev += __shfl_xor(ev, 1);
    ev += __shfl_xor(ev, 2);
    ev += __shfl_xor(ev, 4);
    ev += __shfl_xor(ev, 8);
    if (act) {
        float ls = mv + __logf(ev);
        float4* dp = (float4*)&out[(size_t)n * 40 + p * 4];
        dp[0] = make_float4(l[0] - ls, l[1] - ls, l[2] - ls, l[3] - ls);
    }
}

extern "C" void kernel_launch(void* const* d_in, const int* in_sizes, int n_in,
                              void* d_out, int out_size, void* d_ws, size_t ws_size,
                              hipStream_t stream) {
    const float* x    = (const float*)d_in[0];
    const float* topo = (const float*)d_in[1];
    const int*   ei   = (const int*)d_in[2];
    const float* W1   = (const float*)d_in[3];
    const float* a_s1 = (const float*)d_in[4];
    const float* a_d1 = (const float*)d_in[5];
    const float* b1   = (const float*)d_in[6];
    const float* W2   = (const float*)d_in[7];
    const float* a_s2 = (const float*)d_in[8];
    const float* a_d2 = (const float*)d_in[9];
    const float* b2   = (const float*)d_in[10];
    float* out = (float*)d_out;

    int N = in_sizes[0] / 128;
    int E = in_sizes[2] / 2;
    const int* esrc = ei;
    const int* edst = ei + E;
    int NBUK = (N + 255) / 256;
    size_t cap = (size_t)NBUK * BUK_CAP;

    char* ws = (char*)d_ws;
    size_t off = 0;
    auto alloc = [&](size_t bytes) -> void* {
        void* p = ws + off;
        off = (off + bytes + 255) & ~(size_t)255;
        return p;
    };
    ushort_t* h1b  = (ushort_t*)alloc((size_t)N * 64 * 2);
    float* as1     = (float*)alloc((size_t)N * 8 * 4);
    float* ad1     = (float*)alloc((size_t)N * 8 * 4);
    float* h2      = (float*)alloc((size_t)N * 64 * 4);
    ushort_t* gb   = (ushort_t*)alloc((size_t)N * 40 * 2);  // 80B rows
    float* as2     = (float*)alloc((size_t)N * 4);
    float* ad2     = (float*)alloc((size_t)N * 4);
    int*   rowptr  = (int*)alloc((size_t)N * 4);
    int*   rowEnd  = (int*)alloc((size_t)N * 4);
    int*   csr     = (int*)alloc(cap * 4);
    unsigned int* tmp = (unsigned int*)alloc(cap * 4);
    int* gCursor   = (int*)alloc((size_t)NBUK * 4);

    hipMemsetAsync(gCursor, 0, (size_t)NBUK * 4, stream);  // count-based cursors
    int nbin = (E + BIN_CHUNK - 1) / BIN_CHUNK;
    k_bin<<<nbin, 256, 0, stream>>>(esrc, edst, gCursor, tmp, E, NBUK);
    k_fill2<<<NBUK, 512, 0, stream>>>(tmp, gCursor, rowptr, rowEnd, csr, N);

    int nbg = (N + 63) / 64;  // 64-node GEMM tiles
    int nb8 = (N + 7) / 8;    // 2 nodes/wave x 4 waves/block (agg kernels)
    k_xform1<<<nbg, 256, 0, stream>>>(x, topo, W1, a_s1, a_d1, h1b, as1, ad1, N);
    k_agg1<<<nb8, 256, 0, stream>>>(h1b, as1, ad1, b1, rowptr, rowEnd, csr, h2, N);
    k_xform2<<<nbg, 256, 0, stream>>>(h2, W2, a_s2, a_d2, gb, as2, ad2, N);
    k_agg2<<<nb8, 256, 0, stream>>>(gb, as2, ad2, b2, rowptr, rowEnd, csr, out, N);
}

// Round 17
// 267.773 us; speedup vs baseline: 1.0611x; 1.0137x over previous
//
#include <hip/hip_runtime.h>
#include <math.h>

// ---------------------------------------------------------------------------
// TopoGAT: 2-layer GAT on MI355X.
// R10: fixed-capacity bucket CSR build; padded CSR with rowptr/rowEnd.
// R14: CSR build — k_bin BIN_CHUNK=4096; k_fill2 512thr + uint4 count pass.
// R21/R22: agg kernels -> 1 wave-wide csr load + all gathers up-front.
// R24/R25: agg kernels -> 2 nodes/wave: agg1 ~48.6, agg2 <48. VERIFIED.
// R27: xform1 WS bf16 LDS (best scalar ~49.5). R28/R29 lessons: bf16-LDS
//      pays only via blocks/CU; unpacks are pure VALU cost otherwise.
// R30: k_xform1 -> MFMA (mfma_f32_16x16x32_bf16), layouts verified by
//      harness (absmax unchanged 0.03125): xform1 left top-5 (<48.6),
//      total 278.8 -> 271.4. VERIFIED WIN.
// R31: same MFMA pattern ported to k_xform2 (K=64 = 2x32 exactly; cols
//      40 -> 48 padded, 3 col-tiles; pad cols zeroed, asrc2/adst2 guarded
//      at col<40). LDS 26.25 -> 15.8KB. as2/ad2 = per-row dot across
//      cl-lanes x 3 tiles, 4-level xor reduce, cl==0 writes. W2-bf16
//      numerics already validated in R29; h2-bf16 rounds before a bf16
//      output. k_agg1 (48.6, HBM 46%/VALU 50%) is near its gather floor.
// ---------------------------------------------------------------------------

#define NBUK_MAX 512
#define BIN_CHUNK 4096
#define BUK_CAP 4608

typedef unsigned short ushort_t;
typedef short bf16x8 __attribute__((ext_vector_type(8)));
typedef float f32x4 __attribute__((ext_vector_type(4)));

__device__ inline unsigned int f2bf(float f) {  // RNE fp32->bf16
    unsigned int u = __float_as_uint(f);
    u += 0x7FFFu + ((u >> 16) & 1u);
    return u >> 16;
}
__device__ inline float bf_lo(unsigned int u) {
    return __uint_as_float(u << 16);
}
__device__ inline float bf_hi(unsigned int u) {
    return __uint_as_float(u & 0xFFFF0000u);
}
__device__ inline float lrelu_exp(float q) {
    return __expf(q >= 0.f ? q : 0.2f * q);
}

__device__ inline int wave_incl_scan(int v, int lane) {
    #pragma unroll
    for (int ofs = 1; ofs < 64; ofs <<= 1) {
        int t = __shfl_up(v, ofs);
        if (lane >= ofs) v += t;
    }
    return v;
}

// Bin edges into fixed-capacity bucket regions of tmp. One global atomic per
// (block,bucket); packed word = (src<<8) | (dst&255). 16 edges/thread via
// int4 loads; dst stashed in registers across the reservation barrier.
__global__ __launch_bounds__(256) void k_bin(const int* __restrict__ src,
                                             const int* __restrict__ dst,
                                             int* __restrict__ gCursor,
                                             unsigned int* __restrict__ tmp,
                                             int E, int NBUK) {
    __shared__ int lcnt[NBUK_MAX];
    __shared__ int lcur[NBUK_MAX];
    int tid = threadIdx.x;
    int base = blockIdx.x * BIN_CHUNK;
    for (int i = tid; i < NBUK; i += 256) lcnt[i] = 0;
    __syncthreads();
    int d[16];
    #pragma unroll
    for (int q = 0; q < 4; q++) {
        int e = base + q * 1024 + 4 * tid;
        if (e + 3 < E) {
            int4 v = *(const int4*)&dst[e];
            d[4 * q + 0] = v.x; d[4 * q + 1] = v.y;
            d[4 * q + 2] = v.z; d[4 * q + 3] = v.w;
        } else {
            #pragma unroll
            for (int k = 0; k < 4; k++)
                d[4 * q + k] = (e + k < E) ? dst[e + k] : -1;
        }
    }
    #pragma unroll
    for (int k = 0; k < 16; k++)
        if (d[k] >= 0) atomicAdd(&lcnt[d[k] >> 8], 1);
    __syncthreads();
    for (int b = tid; b < NBUK; b += 256) {
        int c = lcnt[b];
        lcur[b] = c ? b * BUK_CAP + atomicAdd(&gCursor[b], c) : 0;
    }
    __syncthreads();
    #pragma unroll
    for (int q = 0; q < 4; q++) {
        int e = base + q * 1024 + 4 * tid;
        int s[4];
        if (e + 3 < E) {
            int4 v = *(const int4*)&src[e];
            s[0] = v.x; s[1] = v.y; s[2] = v.z; s[3] = v.w;
        } else {
            #pragma unroll
            for (int k = 0; k < 4; k++)
                s[k] = (e + k < E) ? src[e + k] : 0;
        }
        #pragma unroll
        for (int k = 0; k < 4; k++) {
            int dd = d[4 * q + k];
            if (dd >= 0) {
                int p = atomicAdd(&lcur[dd >> 8], 1);
                tmp[p] = ((unsigned int)s[k] << 8) | (unsigned int)(dd & 255);
            }
        }
    }
}

// Exact CSR fill within a bucket (padded layout, base = b*BUK_CAP).
// 512 threads; count pass reads tmp as uint4.
__global__ __launch_bounds__(512) void k_fill2(const unsigned int* __restrict__ tmp,
                                               const int* __restrict__ gCursor,
                                               int* __restrict__ rowptr,
                                               int* __restrict__ rowEnd,
                                               int* __restrict__ csr, int N) {
    __shared__ int cnt[256];
    __shared__ int cur[256];
    __shared__ int wsum[4];
    int b = blockIdx.x, tid = threadIdx.x;
    int e0 = b * BUK_CAP;
    int cnt_e = gCursor[b];       // bucket edge count
    int e1 = e0 + cnt_e;
    if (tid < 256) cnt[tid] = 0;
    __syncthreads();
    {   // count pass: uint4 over the bulk (e0 is 16B-aligned: BUK_CAP*4 % 16 == 0)
        int nq = cnt_e >> 2;
        const uint4* t4 = (const uint4*)(tmp + e0);
        for (int q = tid; q < nq; q += 512) {
            uint4 v = t4[q];
            atomicAdd(&cnt[v.x & 255u], 1);
            atomicAdd(&cnt[v.y & 255u], 1);
            atomicAdd(&cnt[v.z & 255u], 1);
            atomicAdd(&cnt[v.w & 255u], 1);
        }
        for (int i = (nq << 2) + tid; i < cnt_e; i += 512)
            atomicAdd(&cnt[tmp[e0 + i] & 255u], 1);
    }
    __syncthreads();
    if (tid < 256) {
        int lane = tid & 63, wv = tid >> 6;
        int v = cnt[tid];
        int incl = wave_incl_scan(v, lane);
        if (lane == 63) wsum[wv] = incl;
        cnt[tid] = incl - v;  // stash exclusive-within-wave
    }
    __syncthreads();
    if (tid < 256) {
        int wv = tid >> 6;
        int woff = 0;
        for (int i = 0; i < wv; i++) woff += wsum[i];
        int excl = woff + cnt[tid];
        int node = b * 256 + tid;
        int start = e0 + excl;
        cur[tid] = start;
        if (node < N) {
            rowptr[node] = start;
        }
    }
    __syncthreads();
    // rowEnd[node] = next start (cur of tid+1) or e1 for the last
    if (tid < 256) {
        int node = b * 256 + tid;
        if (node < N) rowEnd[node] = (tid < 255) ? cur[tid + 1] : e1;
    }
    __syncthreads();
    for (int i = e0 + tid; i < e1; i += 512) {
        unsigned int t = tmp[i];
        int p = atomicAdd(&cur[t & 255u], 1);
        csr[p] = (int)(t >> 8);
    }
}

// h1b[n][64](bf16) = [x[n]|topo[n]] @ W1 via MFMA; as1/ad1 from C-frags.
// Block = 64 nodes x 64 cols, K=136 zero-padded to 160. A=[node][k] bf16,
// B=W1^T=[col][k] bf16 in LDS (pitch 168 -> 2-way-free reads; 43KB total).
// 4 waves: wave w owns rows 16w..16w+15, computes 4 col-tiles. (R30 VERIFIED)
__global__ __launch_bounds__(256) void k_xform1(const float* __restrict__ x,
                                                const float* __restrict__ topo,
                                                const float* __restrict__ W1,
                                                const float* __restrict__ asrc,
                                                const float* __restrict__ adst,
                                                ushort_t* __restrict__ h1b,
                                                float* __restrict__ as1,
                                                float* __restrict__ ad1, int N) {
    __shared__ ushort_t XA[64 * 168];  // [node][k] bf16 (21.5KB)
    __shared__ ushort_t WB[64 * 168];  // [col][k]  bf16 (21.5KB)
    unsigned int* XAu = (unsigned int*)XA;
    unsigned int* WBu = (unsigned int*)WB;
    int tid = threadIdx.x;
    int n0 = blockIdx.x * 64;
    // stage x (k 0..127) as bf16 pairs, row-major per node
    const float4* x4 = (const float4*)x;
    for (int i = tid; i < 2048; i += 256) {
        int nd = i >> 5, q = i & 31;
        int gn = n0 + nd; if (gn > N - 1) gn = N - 1;
        float4 v = x4[(size_t)gn * 32 + q];
        XAu[nd * 84 + 2 * q]     = f2bf(v.x) | (f2bf(v.y) << 16);
        XAu[nd * 84 + 2 * q + 1] = f2bf(v.z) | (f2bf(v.w) << 16);
    }
    // topo (k 128..135)
    const float4* t4 = (const float4*)topo;
    for (int i = tid; i < 128; i += 256) {
        int nd = i >> 1, q = i & 1;
        int gn = n0 + nd; if (gn > N - 1) gn = N - 1;
        float4 v = t4[(size_t)gn * 2 + q];
        XAu[nd * 84 + 64 + 2 * q]     = f2bf(v.x) | (f2bf(v.y) << 16);
        XAu[nd * 84 + 64 + 2 * q + 1] = f2bf(v.z) | (f2bf(v.w) << 16);
    }
    // zero pad k 136..167
    for (int i = tid; i < 1024; i += 256) {
        int nd = i >> 4, q = i & 15;
        XAu[nd * 84 + 68 + q] = 0;
    }
    // stage W1 transposed: WB[c][k] = W1[k][c] (coalesced over c)
    {
        int c = tid & 63;
        for (int k = tid >> 6; k < 136; k += 4)
            WB[c * 168 + k] = (ushort_t)f2bf(W1[k * 64 + c]);
    }
    for (int i = tid; i < 1024; i += 256) {
        int c = i >> 4, q = i & 15;
        WBu[c * 84 + 68 + q] = 0;
    }
    __syncthreads();
    int w = tid >> 6, l = tid & 63;
    int cl = l & 15;
    int arow = (w << 4) + cl;          // A-frag row (node within block)
    int kb0 = (l >> 4) << 3;           // lane k-base within a 32-K step
    f32x4 acc0 = {0.f, 0.f, 0.f, 0.f};
    f32x4 acc1 = acc0, acc2 = acc0, acc3 = acc0;
    #pragma unroll
    for (int ks = 0; ks < 5; ks++) {
        int kb = kb0 + (ks << 5);
        bf16x8 af = *(const bf16x8*)&XA[arow * 168 + kb];
        bf16x8 b0 = *(const bf16x8*)&WB[(cl)      * 168 + kb];
        bf16x8 b1 = *(const bf16x8*)&WB[(16 + cl) * 168 + kb];
        bf16x8 b2 = *(const bf16x8*)&WB[(32 + cl) * 168 + kb];
        bf16x8 b3 = *(const bf16x8*)&WB[(48 + cl) * 168 + kb];
        acc0 = __builtin_amdgcn_mfma_f32_16x16x32_bf16(af, b0, acc0, 0, 0, 0);
        acc1 = __builtin_amdgcn_mfma_f32_16x16x32_bf16(af, b1, acc1, 0, 0, 0);
        acc2 = __builtin_amdgcn_mfma_f32_16x16x32_bf16(af, b2, acc2, 0, 0, 0);
        acc3 = __builtin_amdgcn_mfma_f32_16x16x32_bf16(af, b3, acc3, 0, 0, 0);
    }
    // epilogue: C layout col=l&15 (per tile), row=(l>>4)*4+reg (HW-verified)
    int rbase = n0 + (w << 4) + ((l >> 4) << 2);
    #pragma unroll
    for (int nt = 0; nt < 4; nt++) {
        f32x4 a = (nt == 0) ? acc0 : (nt == 1) ? acc1 : (nt == 2) ? acc2 : acc3;
        int col = (nt << 4) + cl;
        float asc = asrc[col], adc = adst[col];
        #pragma unroll
        for (int r = 0; r < 4; r++) {
            int n = rbase + r;
            if (n < N) h1b[(size_t)n * 64 + col] = (ushort_t)f2bf(a[r]);
            float s = a[r] * asc;
            float dd = a[r] * adc;
            s += __shfl_xor(s, 1); s += __shfl_xor(s, 2); s += __shfl_xor(s, 4);
            dd += __shfl_xor(dd, 1); dd += __shfl_xor(dd, 2); dd += __shfl_xor(dd, 4);
            if ((l & 7) == 0 && n < N) {
                int head = col >> 3;
                as1[n * 8 + head] = s;
                ad1[n * 8 + head] = dd;
            }
        }
    }
}

// NOTE: parameter names W_/U_ must not collide with vector members .x/.y/.z/.w
#define AGG_FMA(W_, U_)                                           \
    {                                                             \
        acc[0] = fmaf(W_, bf_lo(U_.x), acc[0]);                   \
        acc[1] = fmaf(W_, bf_hi(U_.x), acc[1]);                   \
        acc[2] = fmaf(W_, bf_lo(U_.y), acc[2]);                   \
        acc[3] = fmaf(W_, bf_hi(U_.y), acc[3]);                   \
        acc[4] = fmaf(W_, bf_lo(U_.z), acc[4]);                   \
        acc[5] = fmaf(W_, bf_hi(U_.z), acc[5]);                   \
        acc[6] = fmaf(W_, bf_lo(U_.w), acc[6]);                   \
        acc[7] = fmaf(W_, bf_hi(U_.w), acc[7]);                   \
        z += W_;                                                  \
    }

// 2-node gather: shfl within this half (nbase = nid*32); se masked to 0 when
// the half's row is empty (d==0) so no garbage-index OOB gather.
#define AGG1_GATHER(EIDX, SE_, AV_, UU_)                                     \
    int SE_ = __shfl(cv, nbase + ((EIDX) < d ? (EIDX) : dm1));               \
    SE_ = d > 0 ? SE_ : 0;                                                   \
    float AV_ = as1[SE_ * 8 + head];                                         \
    uint4 UU_ = *(const uint4*)(h1c + (((unsigned)SE_ << 7) + hoff));

#define AGG1_COMP(EIDX, AV_, UU_)                                            \
    {                                                                        \
        float w_ = (EIDX) < d ? lrelu_exp(AV_ + adv) : 0.f;                  \
        AGG_FMA(w_, UU_);                                                    \
    }

// Per-dst softmax-weighted aggregation, layer 1 (+ implicit self loop).
// R24: TWO nodes per wave. Lanes 0-31 = node A, 32-63 = node B; within a
// half: 4 edge slots x 8 heads on 128B rows. One wave-wide csr load covers
// 32 edges/node; gathers for chunks 0-5 (24 edges) issue up-front; compute
// chunks gated by wave-uniform dmax. Reduce = 2 shfl levels (xor 8/16).
__global__ __launch_bounds__(256) void k_agg1(const ushort_t* __restrict__ h1b,
                                              const float* __restrict__ as1,
                                              const float* __restrict__ ad1,
                                              const float* __restrict__ b1,
                                              const int* __restrict__ rowptr,
                                              const int* __restrict__ rowEnd,
                                              const int* __restrict__ csr,
                                              float* __restrict__ h2, int N) {
    int tid = threadIdx.x, lane = tid & 63;
    int nbase0 = blockIdx.x * 8 + ((tid >> 6) << 1);
    if (nbase0 >= N) return;              // wave-uniform
    int nid = lane >> 5;                  // node within wave (0/1)
    int nbase = nid << 5;                 // shfl base for this half
    int l32 = lane & 31;
    int g = (lane >> 3) & 3;              // edge slot 0..3
    int head = lane & 7;                  // head (cols 8h..8h+7)
    int n = nbase0 + nid;
    bool valid = n < N;
    int nc = valid ? n : N - 1;
    const char* h1c = (const char*)h1b;
    unsigned hoff = (unsigned)head << 4;  // 16B per head block
    float adv = ad1[nc * 8 + head];
    float acc[8];
    #pragma unroll
    for (int k = 0; k < 8; k++) acc[k] = 0.f;
    float z = 0.f;

    int j0 = rowptr[nc], j1 = rowEnd[nc];
    int d = valid ? (j1 - j0) : 0;
    int dm1 = d > 0 ? d - 1 : 0;
    int dx = __shfl_xor(d, 32);
    int dmax = d > dx ? d : dx;           // wave-uniform branch driver
    // ONE wave-wide csr load: 32 edges per node (value garbage if d==0;
    // address always in-bounds; masked at se stage)
    int cv = csr[j0 + (l32 < d ? l32 : dm1)];

    {   // self loop (g==0 lanes of each half: 16/64 active)
        float w = lrelu_exp(as1[nc * 8 + head] + adv);
        if (g == 0 && valid) {
            uint4 u = *(const uint4*)(h1c + (((unsigned)nc << 7) + hoff));
            acc[0] = w * bf_lo(u.x); acc[1] = w * bf_hi(u.x);
            acc[2] = w * bf_lo(u.y); acc[3] = w * bf_hi(u.y);
            acc[4] = w * bf_lo(u.z); acc[5] = w * bf_hi(u.z);
            acc[6] = w * bf_lo(u.w); acc[7] = w * bf_hi(u.w);
            z = w;
        }
    }
    if (dmax > 0) {
        // gathers for chunks 0..5 (edges 0..23 per node), 1 round trip
        int e0 = g, e1 = 4 + g, e2 = 8 + g, e3 = 12 + g, e4 = 16 + g, e5 = 20 + g;
        AGG1_GATHER(e0, s0, a0, u0)
        AGG1_GATHER(e1, s1, a1, u1)
        AGG1_GATHER(e2, s2, a2, u2)
        AGG1_GATHER(e3, s3, a3, u3)
        AGG1_GATHER(e4, s4, a4, u4)
        AGG1_GATHER(e5, s5, a5, u5)
        AGG1_COMP(e0, a0, u0)
        if (dmax > 4)  AGG1_COMP(e1, a1, u1)
        if (dmax > 8)  AGG1_COMP(e2, a2, u2)
        if (dmax > 12) AGG1_COMP(e3, a3, u3)
        if (dmax > 16) AGG1_COMP(e4, a4, u4)
        if (dmax > 20) AGG1_COMP(e5, a5, u5)
        if (dmax > 24) {                  // chunks 6/7 (edges 24..31)
            int e6 = 24 + g, e7 = 28 + g;
            AGG1_GATHER(e6, s6, a6, u6)
            AGG1_GATHER(e7, s7, a7, u7)
            AGG1_COMP(e6, a6, u6)
            if (dmax > 28) AGG1_COMP(e7, a7, u7)
            if (dmax > 32) {              // rare fallback: direct per-lane loads
                for (int eb = 32; eb < dmax; eb += 4) {
                    int e = eb + g;
                    int idx = e < d ? e : dm1;
                    int se = csr[j0 + idx];
                    se = d > 0 ? se : 0;
                    float av = as1[se * 8 + head];
                    uint4 u = *(const uint4*)(h1c + (((unsigned)se << 7) + hoff));
                    float w = e < d ? lrelu_exp(av + adv) : 0.f;
                    AGG_FMA(w, u);
                }
            }
        }
    }
    // reduce across the 4 edge-slot groups of each half (xor 8, 16 stay in-half)
    #pragma unroll
    for (int k = 0; k < 8; k++) {
        acc[k] += __shfl_xor(acc[k], 8);
        acc[k] += __shfl_xor(acc[k], 16);
    }
    z += __shfl_xor(z, 8); z += __shfl_xor(z, 16);
    if (g == 0 && valid) {
        float inv = 1.f / (z + 1e-16f);
        float o[8];
        #pragma unroll
        for (int k = 0; k < 8; k++) {
            float v = acc[k] * inv + b1[head * 8 + k];
            o[k] = v > 0.f ? v : (__expf(v) - 1.f);
        }
        float4* dp = (float4*)&h2[(size_t)n * 64 + head * 8];
        dp[0] = make_float4(o[0], o[1], o[2], o[3]);
        dp[1] = make_float4(o[4], o[5], o[6], o[7]);
    }
}

// gb[n][40](bf16) = h2[n] @ W2 via MFMA (R31; same verified pattern as R30).
// Block = 64 nodes x 48 cols (40 real + 8 zero pad), K=64 = 2x32 steps.
// A=h2[node][k] bf16, B=W2^T=[col][k] bf16 in LDS (pitch 72; 15.8KB).
// 4 waves x 3 col-tiles. as2/ad2: per-row dot across cl lanes x 3 tiles,
// 4-level xor reduce, cl==0 writes.
__global__ __launch_bounds__(256) void k_xform2(const float* __restrict__ h2,
                                                const float* __restrict__ W2,
                                                const float* __restrict__ asrc2,
                                                const float* __restrict__ adst2,
                                                ushort_t* __restrict__ gb,
                                                float* __restrict__ as2,
                                                float* __restrict__ ad2, int N) {
    __shared__ ushort_t XA[64 * 72];   // [node][k] bf16 (9.2KB)
    __shared__ ushort_t WB[48 * 72];   // [col][k]  bf16 (6.9KB)
    unsigned int* XAu = (unsigned int*)XA;
    int tid = threadIdx.x;
    int n0 = blockIdx.x * 64;
    // stage h2 as bf16, row-major per node (64 nodes x 16 float4)
    const float4* h4 = (const float4*)h2;
    for (int i = tid; i < 1024; i += 256) {
        int nd = i >> 4, q = i & 15;
        int gn = n0 + nd; if (gn > N - 1) gn = N - 1;
        float4 v = h4[(size_t)gn * 16 + q];
        XAu[nd * 36 + 2 * q]     = f2bf(v.x) | (f2bf(v.y) << 16);
        XAu[nd * 36 + 2 * q + 1] = f2bf(v.z) | (f2bf(v.w) << 16);
    }
    // stage W2 transposed: WB[c][k] = W2[k][c]; cols 40..47 zero
    for (int i = tid; i < 48 * 64; i += 256) {
        int c = i >> 6, k = i & 63;
        float val = (c < 40) ? W2[k * 40 + c] : 0.f;
        WB[c * 72 + k] = (ushort_t)f2bf(val);
    }
    __syncthreads();
    int w = tid >> 6, l = tid & 63;
    int cl = l & 15;
    int arow = (w << 4) + cl;
    int kb0 = (l >> 4) << 3;
    f32x4 acc0 = {0.f, 0.f, 0.f, 0.f};
    f32x4 acc1 = acc0, acc2 = acc0;
    #pragma unroll
    for (int ks = 0; ks < 2; ks++) {
        int kb = kb0 + (ks << 5);
        bf16x8 af = *(const bf16x8*)&XA[arow * 72 + kb];
        bf16x8 b0 = *(const bf16x8*)&WB[(cl)      * 72 + kb];
        bf16x8 b1 = *(const bf16x8*)&WB[(16 + cl) * 72 + kb];
        bf16x8 b2 = *(const bf16x8*)&WB[(32 + cl) * 72 + kb];
        acc0 = __builtin_amdgcn_mfma_f32_16x16x32_bf16(af, b0, acc0, 0, 0, 0);
        acc1 = __builtin_amdgcn_mfma_f32_16x16x32_bf16(af, b1, acc1, 0, 0, 0);
        acc2 = __builtin_amdgcn_mfma_f32_16x16x32_bf16(af, b2, acc2, 0, 0, 0);
    }
    // epilogue: C layout col=cl (per tile), row=(l>>4)*4+reg
    int rbase = n0 + (w << 4) + ((l >> 4) << 2);
    int col0 = cl, col1 = 16 + cl, col2 = 32 + cl;
    float as0 = asrc2[col0], ad0 = adst2[col0];
    float as1c = asrc2[col1], ad1c = adst2[col1];
    float as2c = (col2 < 40) ? asrc2[col2] : 0.f;
    float ad2c = (col2 < 40) ? adst2[col2] : 0.f;
    #pragma unroll
    for (int r = 0; r < 4; r++) {
        int n = rbase + r;
        bool vn = n < N;
        if (vn) {
            gb[(size_t)n * 40 + col0] = (ushort_t)f2bf(acc0[r]);
            gb[(size_t)n * 40 + col1] = (ushort_t)f2bf(acc1[r]);
            if (col2 < 40) gb[(size_t)n * 40 + col2] = (ushort_t)f2bf(acc2[r]);
        }
        float s = acc0[r] * as0 + acc1[r] * as1c + acc2[r] * as2c;
        float dd = acc0[r] * ad0 + acc1[r] * ad1c + acc2[r] * ad2c;
        s += __shfl_xor(s, 1); s += __shfl_xor(s, 2);
        s += __shfl_xor(s, 4); s += __shfl_xor(s, 8);
        dd += __shfl_xor(dd, 1); dd += __shfl_xor(dd, 2);
        dd += __shfl_xor(dd, 4); dd += __shfl_xor(dd, 8);
        if (cl == 0 && vn) { as2[n] = s; ad2[n] = dd; }
    }
}

// 2-node agg2 gather: uint2 (4 cols) of row se at this lane's col block.
// se masked to 0 when the half's row is empty (d==0).
#define AGG2_G(C_, SE_, AV_, UU_)                                            \
    int ee##C_ = 3 * (C_) + gg;                                              \
    int SE_ = __shfl(cv, nbase + (ee##C_ < d ? ee##C_ : dm1));               \
    SE_ = d > 0 ? SE_ : 0;                                                   \
    float AV_ = as2[SE_];                                                    \
    uint2 UU_ = *(const uint2*)(gbc + (unsigned)SE_ * 80u + poff);

#define AGG2_K(C_, AV_, UU_)                                                 \
    {                                                                        \
        float w_ = (ee##C_ < d) ? lrelu_exp(AV_ + add) : 0.f;                \
        acc[0] = fmaf(w_, bf_lo(UU_.x), acc[0]);                             \
        acc[1] = fmaf(w_, bf_hi(UU_.x), acc[1]);                             \
        acc[2] = fmaf(w_, bf_lo(UU_.y), acc[2]);                             \
        acc[3] = fmaf(w_, bf_hi(UU_.y), acc[3]);                             \
        z += w_;                                                             \
    }

// Layer-2 aggregation + bias + log_softmax. (R25-verified structure.)
__global__ __launch_bounds__(256) void k_agg2(const ushort_t* __restrict__ gb,
                                              const float* __restrict__ as2,
                                              const float* __restrict__ ad2,
                                              const float* __restrict__ b2,
                                              const int* __restrict__ rowptr,
                                              const int* __restrict__ rowEnd,
                                              const int* __restrict__ csr,
                                              float* __restrict__ out, int N) {
    int tid = threadIdx.x, lane = tid & 63;
    int nbase0 = blockIdx.x * 8 + ((tid >> 6) << 1);
    if (nbase0 >= N) return;              // wave-uniform
    int nid = lane >> 5;                  // node within wave (0/1)
    int nbase = nid << 5;                 // shfl base for this half
    int l32 = lane & 31;
    int gg = l32 / 10;                    // edge slot 0..2 (lanes 30/31 dup)
    int p = l32 - gg * 10;                // col block (4 cols each)
    if (gg > 2) { gg = 2; p = 9; }        // lanes 30,31: duplicate, unread
    int n = nbase0 + nid;
    bool valid = n < N;
    int nc = valid ? n : N - 1;
    const char* gbc = (const char*)gb;
    unsigned poff = (unsigned)p << 3;     // 8B per col block
    float add = ad2[nc];
    float acc[4] = {0.f, 0.f, 0.f, 0.f};
    float z = 0.f;

    int j0 = rowptr[nc], j1 = rowEnd[nc];
    int d = valid ? (j1 - j0) : 0;
    int dm1 = d > 0 ? d - 1 : 0;
    int dxx = __shfl_xor(d, 32);
    int dmax = d > dxx ? d : dxx;         // wave-uniform branch driver
    // ONE wave-wide csr load: 32 edges per node (masked at se stage)
    int cv = csr[j0 + (l32 < d ? l32 : dm1)];

    {   // self loop (gg==0 lanes of each half)
        float w = lrelu_exp(as2[nc] + add);
        if (gg == 0 && valid) {
            uint2 u = *(const uint2*)(gbc + (unsigned)nc * 80u + poff);
            acc[0] = w * bf_lo(u.x); acc[1] = w * bf_hi(u.x);
            acc[2] = w * bf_lo(u.y); acc[3] = w * bf_hi(u.y);
            z = w;
        }
    }
    if (dmax > 0) {
        // gathers for chunks 0..7 (edges 0..23 per node), 1 round trip
        AGG2_G(0, s0, a0, u0)
        AGG2_G(1, s1, a1, u1)
        AGG2_G(2, s2, a2, u2)
        AGG2_G(3, s3, a3, u3)
        AGG2_G(4, s4, a4, u4)
        AGG2_G(5, s5, a5, u5)
        AGG2_G(6, s6, a6, u6)
        AGG2_G(7, s7, a7, u7)
        AGG2_K(0, a0, u0)
        if (dmax > 3)  AGG2_K(1, a1, u1)
        if (dmax > 6)  AGG2_K(2, a2, u2)
        if (dmax > 9)  AGG2_K(3, a3, u3)
        if (dmax > 12) AGG2_K(4, a4, u4)
        if (dmax > 15) AGG2_K(5, a5, u5)
        if (dmax > 18) AGG2_K(6, a6, u6)
        if (dmax > 21) AGG2_K(7, a7, u7)
        if (dmax > 24) {                  // chunks 8/9 (edges 24..29)
            AGG2_G(8, s8, a8, u8)
            AGG2_G(9, s9, a9, u9)
            AGG2_K(8, a8, u8)
            if (dmax > 27) AGG2_K(9, a9, u9)
            if (dmax > 30) {              // rare fallback: direct per-lane loads
                for (int eb = 30; eb < dmax; eb += 3) {
                    int e = eb + gg;
                    int idx = e < d ? e : dm1;
                    int se = csr[j0 + idx];
                    se = d > 0 ? se : 0;
                    float av = as2[se];
                    uint2 u = *(const uint2*)(gbc + (unsigned)se * 80u + poff);
                    float w = (e < d) ? lrelu_exp(av + add) : 0.f;
                    acc[0] = fmaf(w, bf_lo(u.x), acc[0]);
                    acc[1] = fmaf(w, bf_hi(u.x), acc[1]);
                    acc[2] = fmaf(w, bf_lo(u.y), acc[2]);
                    acc[3] = fmaf(w, bf_hi(u.y), acc[3]);
                    z += w;
                }
            }
        }
    }
    // reduce across the 3 slot groups: A(p) = v(p) + v(p+10) + v(p+20).
    // Both shfls read the ORIGINAL value; result valid at lanes p<10 of
    // each half (reads stay within the half there).
    #pragma unroll
    for (int k = 0; k < 4; k++) {
        float t1 = __shfl(acc[k], lane + 10);
        float t2 = __shfl(acc[k], lane + 20);
        acc[k] += t1 + t2;
    }
    {
        float t1 = __shfl(z, lane + 10);
        float t2 = __shfl(z, lane + 20);
        z += t1 + t2;
    }
    // epilogue: lanes l32<10 hold 4 logits each (cols 4p..4p+3);
    // butterfly over each half's first 16 lanes (xor 1/2/4/8 stays inside)
    bool act = (l32 < 10) && valid;
    float l[4];
    float mv = -INFINITY;
    if (act) {
        float inv = 1.f / (z + 1e-16f);
        #pragma unroll
        for (int k = 0; k < 4; k++) {
            l[k] = acc[k] * inv + b2[p * 4 + k];
            mv = fmaxf(mv, l[k]);
        }
    }
    mv = fmaxf(mv, __shfl_xor(mv, 1));
    mv = fmaxf(mv, __shfl_xor(mv, 2));
    mv = fmaxf(mv, __shfl_xor(mv, 4));
    mv = fmaxf(mv, __shfl_xor(mv, 8));
    float ev = 0.f;
    if (act) {
        #pragma unroll
        for (int k = 0; k < 4; k++) ev += __expf(l[k] - mv);
    }
    ev += __shfl_xor(ev, 1);
    ev += __shfl_xor(ev, 2);
    ev += __shfl_xor(ev, 4);
    ev += __shfl_xor(ev, 8);
    if (act) {
        float ls = mv + __logf(ev);
        float4* dp = (float4*)&out[(size_t)n * 40 + p * 4];
        dp[0] = make_float4(l[0] - ls, l[1] - ls, l[2] - ls, l[3] - ls);
    }
}

extern "C" void kernel_launch(void* const* d_in, const int* in_sizes, int n_in,
                              void* d_out, int out_size, void* d_ws, size_t ws_size,
                              hipStream_t stream) {
    const float* x    = (const float*)d_in[0];
    const float* topo = (const float*)d_in[1];
    const int*   ei   = (const int*)d_in[2];
    const float* W1   = (const float*)d_in[3];
    const float* a_s1 = (const float*)d_in[4];
    const float* a_d1 = (const float*)d_in[5];
    const float* b1   = (const float*)d_in[6];
    const float* W2   = (const float*)d_in[7];
    const float* a_s2 = (const float*)d_in[8];
    const float* a_d2 = (const float*)d_in[9];
    const float* b2   = (const float*)d_in[10];
    float* out = (float*)d_out;

    int N = in_sizes[0] / 128;
    int E = in_sizes[2] / 2;
    const int* esrc = ei;
    const int* edst = ei + E;
    int NBUK = (N + 255) / 256;
    size_t cap = (size_t)NBUK * BUK_CAP;

    char* ws = (char*)d_ws;
    size_t off = 0;
    auto alloc = [&](size_t bytes) -> void* {
        void* p = ws + off;
        off = (off + bytes + 255) & ~(size_t)255;
        return p;
    };
    ushort_t* h1b  = (ushort_t*)alloc((size_t)N * 64 * 2);
    float* as1     = (float*)alloc((size_t)N * 8 * 4);
    float* ad1     = (float*)alloc((size_t)N * 8 * 4);
    float* h2      = (float*)alloc((size_t)N * 64 * 4);
    ushort_t* gb   = (ushort_t*)alloc((size_t)N * 40 * 2);  // 80B rows
    float* as2     = (float*)alloc((size_t)N * 4);
    float* ad2     = (float*)alloc((size_t)N * 4);
    int*   rowptr  = (int*)alloc((size_t)N * 4);
    int*   rowEnd  = (int*)alloc((size_t)N * 4);
    int*   csr     = (int*)alloc(cap * 4);
    unsigned int* tmp = (unsigned int*)alloc(cap * 4);
    int* gCursor   = (int*)alloc((size_t)NBUK * 4);

    hipMemsetAsync(gCursor, 0, (size_t)NBUK * 4, stream);  // count-based cursors
    int nbin = (E + BIN_CHUNK - 1) / BIN_CHUNK;
    k_bin<<<nbin, 256, 0, stream>>>(esrc, edst, gCursor, tmp, E, NBUK);
    k_fill2<<<NBUK, 512, 0, stream>>>(tmp, gCursor, rowptr, rowEnd, csr, N);

    int nbg = (N + 63) / 64;  // 64-node GEMM tiles
    int nb8 = (N + 7) / 8;    // 2 nodes/wave x 4 waves/block (agg kernels)
    k_xform1<<<nbg, 256, 0, stream>>>(x, topo, W1, a_s1, a_d1, h1b, as1, ad1, N);
    k_agg1<<<nb8, 256, 0, stream>>>(h1b, as1, ad1, b1, rowptr, rowEnd, csr, h2, N);
    k_xform2<<<nbg, 256, 0, stream>>>(h2, W2, a_s2, a_d2, gb, as2, ad2, N);
    k_agg2<<<nb8, 256, 0, stream>>>(gb, as2, ad2, b2, rowptr, rowEnd, csr, out, N);
}

// Round 18
// 264.837 us; speedup vs baseline: 1.0729x; 1.0111x over previous
//
#include <hip/hip_runtime.h>
#include <math.h>

// ---------------------------------------------------------------------------
// TopoGAT: 2-layer GAT on MI355X.
// R10/R14: bucket CSR build (k_bin BIN_CHUNK=4096; k_fill2 512thr).
// R21/R22: agg kernels -> 1 wave-wide csr load + all gathers up-front.
// R24/R25: agg kernels -> 2 nodes/wave. VERIFIED.
// R30/R31: both xforms -> MFMA (mfma_f32_16x16x32_bf16), absmax unchanged
//      0.03125: total 278.8 -> 271.4 -> 267.8. VERIFIED WINS.
// R32: two provably-equivalent micro-changes:
//      (a) h2 stored bf16 (h2b). xform2 ALREADY quantized h2 to bf16 at
//          staging; moving the same RNE f2bf into agg1's epilogue makes XA
//          bit-identical while halving agg1 WRITE (25->12.5MB), halving
//          xform2's h2 fetch, and making xform2 staging a bit-copy.
//      (b) redundant per-gather clamp removed in AGG1_GATHER/AGG2_G: the
//          wave-wide csr load is already index-clamped, so lane e of cv
//          holds csr[e<d?e:dm1]; the second select recomputed it. Value-
//          identical; ~16 VALU/wave saved in 50%-VALU kernels.
//      Expected: absmax EXACTLY 0.03125; agg1 WRITE_SIZE halves.
// ---------------------------------------------------------------------------

#define NBUK_MAX 512
#define BIN_CHUNK 4096
#define BUK_CAP 4608

typedef unsigned short ushort_t;
typedef short bf16x8 __attribute__((ext_vector_type(8)));
typedef float f32x4 __attribute__((ext_vector_type(4)));

__device__ inline unsigned int f2bf(float f) {  // RNE fp32->bf16
    unsigned int u = __float_as_uint(f);
    u += 0x7FFFu + ((u >> 16) & 1u);
    return u >> 16;
}
__device__ inline float bf_lo(unsigned int u) {
    return __uint_as_float(u << 16);
}
__device__ inline float bf_hi(unsigned int u) {
    return __uint_as_float(u & 0xFFFF0000u);
}
__device__ inline float lrelu_exp(float q) {
    return __expf(q >= 0.f ? q : 0.2f * q);
}

__device__ inline int wave_incl_scan(int v, int lane) {
    #pragma unroll
    for (int ofs = 1; ofs < 64; ofs <<= 1) {
        int t = __shfl_up(v, ofs);
        if (lane >= ofs) v += t;
    }
    return v;
}

// Bin edges into fixed-capacity bucket regions of tmp. One global atomic per
// (block,bucket); packed word = (src<<8) | (dst&255). 16 edges/thread via
// int4 loads; dst stashed in registers across the reservation barrier.
__global__ __launch_bounds__(256) void k_bin(const int* __restrict__ src,
                                             const int* __restrict__ dst,
                                             int* __restrict__ gCursor,
                                             unsigned int* __restrict__ tmp,
                                             int E, int NBUK) {
    __shared__ int lcnt[NBUK_MAX];
    __shared__ int lcur[NBUK_MAX];
    int tid = threadIdx.x;
    int base = blockIdx.x * BIN_CHUNK;
    for (int i = tid; i < NBUK; i += 256) lcnt[i] = 0;
    __syncthreads();
    int d[16];
    #pragma unroll
    for (int q = 0; q < 4; q++) {
        int e = base + q * 1024 + 4 * tid;
        if (e + 3 < E) {
            int4 v = *(const int4*)&dst[e];
            d[4 * q + 0] = v.x; d[4 * q + 1] = v.y;
            d[4 * q + 2] = v.z; d[4 * q + 3] = v.w;
        } else {
            #pragma unroll
            for (int k = 0; k < 4; k++)
                d[4 * q + k] = (e + k < E) ? dst[e + k] : -1;
        }
    }
    #pragma unroll
    for (int k = 0; k < 16; k++)
        if (d[k] >= 0) atomicAdd(&lcnt[d[k] >> 8], 1);
    __syncthreads();
    for (int b = tid; b < NBUK; b += 256) {
        int c = lcnt[b];
        lcur[b] = c ? b * BUK_CAP + atomicAdd(&gCursor[b], c) : 0;
    }
    __syncthreads();
    #pragma unroll
    for (int q = 0; q < 4; q++) {
        int e = base + q * 1024 + 4 * tid;
        int s[4];
        if (e + 3 < E) {
            int4 v = *(const int4*)&src[e];
            s[0] = v.x; s[1] = v.y; s[2] = v.z; s[3] = v.w;
        } else {
            #pragma unroll
            for (int k = 0; k < 4; k++)
                s[k] = (e + k < E) ? src[e + k] : 0;
        }
        #pragma unroll
        for (int k = 0; k < 4; k++) {
            int dd = d[4 * q + k];
            if (dd >= 0) {
                int p = atomicAdd(&lcur[dd >> 8], 1);
                tmp[p] = ((unsigned int)s[k] << 8) | (unsigned int)(dd & 255);
            }
        }
    }
}

// Exact CSR fill within a bucket (padded layout, base = b*BUK_CAP).
// 512 threads; count pass reads tmp as uint4.
__global__ __launch_bounds__(512) void k_fill2(const unsigned int* __restrict__ tmp,
                                               const int* __restrict__ gCursor,
                                               int* __restrict__ rowptr,
                                               int* __restrict__ rowEnd,
                                               int* __restrict__ csr, int N) {
    __shared__ int cnt[256];
    __shared__ int cur[256];
    __shared__ int wsum[4];
    int b = blockIdx.x, tid = threadIdx.x;
    int e0 = b * BUK_CAP;
    int cnt_e = gCursor[b];       // bucket edge count
    int e1 = e0 + cnt_e;
    if (tid < 256) cnt[tid] = 0;
    __syncthreads();
    {   // count pass: uint4 over the bulk (e0 is 16B-aligned: BUK_CAP*4 % 16 == 0)
        int nq = cnt_e >> 2;
        const uint4* t4 = (const uint4*)(tmp + e0);
        for (int q = tid; q < nq; q += 512) {
            uint4 v = t4[q];
            atomicAdd(&cnt[v.x & 255u], 1);
            atomicAdd(&cnt[v.y & 255u], 1);
            atomicAdd(&cnt[v.z & 255u], 1);
            atomicAdd(&cnt[v.w & 255u], 1);
        }
        for (int i = (nq << 2) + tid; i < cnt_e; i += 512)
            atomicAdd(&cnt[tmp[e0 + i] & 255u], 1);
    }
    __syncthreads();
    if (tid < 256) {
        int lane = tid & 63, wv = tid >> 6;
        int v = cnt[tid];
        int incl = wave_incl_scan(v, lane);
        if (lane == 63) wsum[wv] = incl;
        cnt[tid] = incl - v;  // stash exclusive-within-wave
    }
    __syncthreads();
    if (tid < 256) {
        int wv = tid >> 6;
        int woff = 0;
        for (int i = 0; i < wv; i++) woff += wsum[i];
        int excl = woff + cnt[tid];
        int node = b * 256 + tid;
        int start = e0 + excl;
        cur[tid] = start;
        if (node < N) {
            rowptr[node] = start;
        }
    }
    __syncthreads();
    // rowEnd[node] = next start (cur of tid+1) or e1 for the last
    if (tid < 256) {
        int node = b * 256 + tid;
        if (node < N) rowEnd[node] = (tid < 255) ? cur[tid + 1] : e1;
    }
    __syncthreads();
    for (int i = e0 + tid; i < e1; i += 512) {
        unsigned int t = tmp[i];
        int p = atomicAdd(&cur[t & 255u], 1);
        csr[p] = (int)(t >> 8);
    }
}

// h1b[n][64](bf16) = [x[n]|topo[n]] @ W1 via MFMA; as1/ad1 from C-frags.
// Block = 64 nodes x 64 cols, K=136 zero-padded to 160. A=[node][k] bf16,
// B=W1^T=[col][k] bf16 in LDS (pitch 168 -> 2-way-free reads; 43KB total).
// 4 waves: wave w owns rows 16w..16w+15, computes 4 col-tiles. (R30 VERIFIED)
__global__ __launch_bounds__(256) void k_xform1(const float* __restrict__ x,
                                                const float* __restrict__ topo,
                                                const float* __restrict__ W1,
                                                const float* __restrict__ asrc,
                                                const float* __restrict__ adst,
                                                ushort_t* __restrict__ h1b,
                                                float* __restrict__ as1,
                                                float* __restrict__ ad1, int N) {
    __shared__ ushort_t XA[64 * 168];  // [node][k] bf16 (21.5KB)
    __shared__ ushort_t WB[64 * 168];  // [col][k]  bf16 (21.5KB)
    unsigned int* XAu = (unsigned int*)XA;
    unsigned int* WBu = (unsigned int*)WB;
    int tid = threadIdx.x;
    int n0 = blockIdx.x * 64;
    // stage x (k 0..127) as bf16 pairs, row-major per node
    const float4* x4 = (const float4*)x;
    for (int i = tid; i < 2048; i += 256) {
        int nd = i >> 5, q = i & 31;
        int gn = n0 + nd; if (gn > N - 1) gn = N - 1;
        float4 v = x4[(size_t)gn * 32 + q];
        XAu[nd * 84 + 2 * q]     = f2bf(v.x) | (f2bf(v.y) << 16);
        XAu[nd * 84 + 2 * q + 1] = f2bf(v.z) | (f2bf(v.w) << 16);
    }
    // topo (k 128..135)
    const float4* t4 = (const float4*)topo;
    for (int i = tid; i < 128; i += 256) {
        int nd = i >> 1, q = i & 1;
        int gn = n0 + nd; if (gn > N - 1) gn = N - 1;
        float4 v = t4[(size_t)gn * 2 + q];
        XAu[nd * 84 + 64 + 2 * q]     = f2bf(v.x) | (f2bf(v.y) << 16);
        XAu[nd * 84 + 64 + 2 * q + 1] = f2bf(v.z) | (f2bf(v.w) << 16);
    }
    // zero pad k 136..167
    for (int i = tid; i < 1024; i += 256) {
        int nd = i >> 4, q = i & 15;
        XAu[nd * 84 + 68 + q] = 0;
    }
    // stage W1 transposed: WB[c][k] = W1[k][c] (coalesced over c)
    {
        int c = tid & 63;
        for (int k = tid >> 6; k < 136; k += 4)
            WB[c * 168 + k] = (ushort_t)f2bf(W1[k * 64 + c]);
    }
    for (int i = tid; i < 1024; i += 256) {
        int c = i >> 4, q = i & 15;
        WBu[c * 84 + 68 + q] = 0;
    }
    __syncthreads();
    int w = tid >> 6, l = tid & 63;
    int cl = l & 15;
    int arow = (w << 4) + cl;          // A-frag row (node within block)
    int kb0 = (l >> 4) << 3;           // lane k-base within a 32-K step
    f32x4 acc0 = {0.f, 0.f, 0.f, 0.f};
    f32x4 acc1 = acc0, acc2 = acc0, acc3 = acc0;
    #pragma unroll
    for (int ks = 0; ks < 5; ks++) {
        int kb = kb0 + (ks << 5);
        bf16x8 af = *(const bf16x8*)&XA[arow * 168 + kb];
        bf16x8 b0 = *(const bf16x8*)&WB[(cl)      * 168 + kb];
        bf16x8 b1 = *(const bf16x8*)&WB[(16 + cl) * 168 + kb];
        bf16x8 b2 = *(const bf16x8*)&WB[(32 + cl) * 168 + kb];
        bf16x8 b3 = *(const bf16x8*)&WB[(48 + cl) * 168 + kb];
        acc0 = __builtin_amdgcn_mfma_f32_16x16x32_bf16(af, b0, acc0, 0, 0, 0);
        acc1 = __builtin_amdgcn_mfma_f32_16x16x32_bf16(af, b1, acc1, 0, 0, 0);
        acc2 = __builtin_amdgcn_mfma_f32_16x16x32_bf16(af, b2, acc2, 0, 0, 0);
        acc3 = __builtin_amdgcn_mfma_f32_16x16x32_bf16(af, b3, acc3, 0, 0, 0);
    }
    // epilogue: C layout col=l&15 (per tile), row=(l>>4)*4+reg (HW-verified)
    int rbase = n0 + (w << 4) + ((l >> 4) << 2);
    #pragma unroll
    for (int nt = 0; nt < 4; nt++) {
        f32x4 a = (nt == 0) ? acc0 : (nt == 1) ? acc1 : (nt == 2) ? acc2 : acc3;
        int col = (nt << 4) + cl;
        float asc = asrc[col], adc = adst[col];
        #pragma unroll
        for (int r = 0; r < 4; r++) {
            int n = rbase + r;
            if (n < N) h1b[(size_t)n * 64 + col] = (ushort_t)f2bf(a[r]);
            float s = a[r] * asc;
            float dd = a[r] * adc;
            s += __shfl_xor(s, 1); s += __shfl_xor(s, 2); s += __shfl_xor(s, 4);
            dd += __shfl_xor(dd, 1); dd += __shfl_xor(dd, 2); dd += __shfl_xor(dd, 4);
            if ((l & 7) == 0 && n < N) {
                int head = col >> 3;
                as1[n * 8 + head] = s;
                ad1[n * 8 + head] = dd;
            }
        }
    }
}

// NOTE: parameter names W_/U_ must not collide with vector members .x/.y/.z/.w
#define AGG_FMA(W_, U_)                                           \
    {                                                             \
        acc[0] = fmaf(W_, bf_lo(U_.x), acc[0]);                   \
        acc[1] = fmaf(W_, bf_hi(U_.x), acc[1]);                   \
        acc[2] = fmaf(W_, bf_lo(U_.y), acc[2]);                   \
        acc[3] = fmaf(W_, bf_hi(U_.y), acc[3]);                   \
        acc[4] = fmaf(W_, bf_lo(U_.z), acc[4]);                   \
        acc[5] = fmaf(W_, bf_hi(U_.z), acc[5]);                   \
        acc[6] = fmaf(W_, bf_lo(U_.w), acc[6]);                   \
        acc[7] = fmaf(W_, bf_hi(U_.w), acc[7]);                   \
        z += W_;                                                  \
    }

// 2-node gather. R32: cv is pre-clamped at load (lane e holds
// csr[e<d?e:dm1]), so shfl by the raw edge index is value-identical —
// the old per-gather select was redundant. se masked to 0 when d==0.
#define AGG1_GATHER(EIDX, SE_, AV_, UU_)                                     \
    int SE_ = __shfl(cv, nbase + (EIDX));                                    \
    SE_ = d > 0 ? SE_ : 0;                                                   \
    float AV_ = as1[SE_ * 8 + head];                                         \
    uint4 UU_ = *(const uint4*)(h1c + (((unsigned)SE_ << 7) + hoff));

#define AGG1_COMP(EIDX, AV_, UU_)                                            \
    {                                                                        \
        float w_ = (EIDX) < d ? lrelu_exp(AV_ + adv) : 0.f;                  \
        AGG_FMA(w_, UU_);                                                    \
    }

// Per-dst softmax-weighted aggregation, layer 1 (+ implicit self loop).
// R24: TWO nodes per wave; R32: h2 output packed bf16 (numerically
// identical: xform2 quantized h2 to bf16 at staging anyway).
__global__ __launch_bounds__(256) void k_agg1(const ushort_t* __restrict__ h1b,
                                              const float* __restrict__ as1,
                                              const float* __restrict__ ad1,
                                              const float* __restrict__ b1,
                                              const int* __restrict__ rowptr,
                                              const int* __restrict__ rowEnd,
                                              const int* __restrict__ csr,
                                              ushort_t* __restrict__ h2b, int N) {
    int tid = threadIdx.x, lane = tid & 63;
    int nbase0 = blockIdx.x * 8 + ((tid >> 6) << 1);
    if (nbase0 >= N) return;              // wave-uniform
    int nid = lane >> 5;                  // node within wave (0/1)
    int nbase = nid << 5;                 // shfl base for this half
    int l32 = lane & 31;
    int g = (lane >> 3) & 3;              // edge slot 0..3
    int head = lane & 7;                  // head (cols 8h..8h+7)
    int n = nbase0 + nid;
    bool valid = n < N;
    int nc = valid ? n : N - 1;
    const char* h1c = (const char*)h1b;
    unsigned hoff = (unsigned)head << 4;  // 16B per head block
    float adv = ad1[nc * 8 + head];
    float acc[8];
    #pragma unroll
    for (int k = 0; k < 8; k++) acc[k] = 0.f;
    float z = 0.f;

    int j0 = rowptr[nc], j1 = rowEnd[nc];
    int d = valid ? (j1 - j0) : 0;
    int dm1 = d > 0 ? d - 1 : 0;
    int dx = __shfl_xor(d, 32);
    int dmax = d > dx ? d : dx;           // wave-uniform branch driver
    // ONE wave-wide csr load: lane e holds csr[e] if e<d else csr[dm1]
    int cv = csr[j0 + (l32 < d ? l32 : dm1)];

    {   // self loop (g==0 lanes of each half: 16/64 active)
        float w = lrelu_exp(as1[nc * 8 + head] + adv);
        if (g == 0 && valid) {
            uint4 u = *(const uint4*)(h1c + (((unsigned)nc << 7) + hoff));
            acc[0] = w * bf_lo(u.x); acc[1] = w * bf_hi(u.x);
            acc[2] = w * bf_lo(u.y); acc[3] = w * bf_hi(u.y);
            acc[4] = w * bf_lo(u.z); acc[5] = w * bf_hi(u.z);
            acc[6] = w * bf_lo(u.w); acc[7] = w * bf_hi(u.w);
            z = w;
        }
    }
    if (dmax > 0) {
        // gathers for chunks 0..5 (edges 0..23 per node), 1 round trip
        int e0 = g, e1 = 4 + g, e2 = 8 + g, e3 = 12 + g, e4 = 16 + g, e5 = 20 + g;
        AGG1_GATHER(e0, s0, a0, u0)
        AGG1_GATHER(e1, s1, a1, u1)
        AGG1_GATHER(e2, s2, a2, u2)
        AGG1_GATHER(e3, s3, a3, u3)
        AGG1_GATHER(e4, s4, a4, u4)
        AGG1_GATHER(e5, s5, a5, u5)
        AGG1_COMP(e0, a0, u0)
        if (dmax > 4)  AGG1_COMP(e1, a1, u1)
        if (dmax > 8)  AGG1_COMP(e2, a2, u2)
        if (dmax > 12) AGG1_COMP(e3, a3, u3)
        if (dmax > 16) AGG1_COMP(e4, a4, u4)
        if (dmax > 20) AGG1_COMP(e5, a5, u5)
        if (dmax > 24) {                  // chunks 6/7 (edges 24..31)
            int e6 = 24 + g, e7 = 28 + g;
            AGG1_GATHER(e6, s6, a6, u6)
            AGG1_GATHER(e7, s7, a7, u7)
            AGG1_COMP(e6, a6, u6)
            if (dmax > 28) AGG1_COMP(e7, a7, u7)
            if (dmax > 32) {              // rare fallback: direct per-lane loads
                for (int eb = 32; eb < dmax; eb += 4) {
                    int e = eb + g;
                    int idx = e < d ? e : dm1;
                    int se = csr[j0 + idx];
                    se = d > 0 ? se : 0;
                    float av = as1[se * 8 + head];
                    uint4 u = *(const uint4*)(h1c + (((unsigned)se << 7) + hoff));
                    float w = e < d ? lrelu_exp(av + adv) : 0.f;
                    AGG_FMA(w, u);
                }
            }
        }
    }
    // reduce across the 4 edge-slot groups of each half (xor 8, 16 stay in-half)
    #pragma unroll
    for (int k = 0; k < 8; k++) {
        acc[k] += __shfl_xor(acc[k], 8);
        acc[k] += __shfl_xor(acc[k], 16);
    }
    z += __shfl_xor(z, 8); z += __shfl_xor(z, 16);
    if (g == 0 && valid) {
        float inv = 1.f / (z + 1e-16f);
        float o[8];
        #pragma unroll
        for (int k = 0; k < 8; k++) {
            float v = acc[k] * inv + b1[head * 8 + k];
            o[k] = v > 0.f ? v : (__expf(v) - 1.f);
        }
        // pack to bf16 (same RNE xform2's staging applied) -> 16B store
        unsigned q0 = f2bf(o[0]) | (f2bf(o[1]) << 16);
        unsigned q1 = f2bf(o[2]) | (f2bf(o[3]) << 16);
        unsigned q2 = f2bf(o[4]) | (f2bf(o[5]) << 16);
        unsigned q3 = f2bf(o[6]) | (f2bf(o[7]) << 16);
        *(uint4*)&h2b[(size_t)n * 64 + head * 8] = make_uint4(q0, q1, q2, q3);
    }
}

// gb[n][40](bf16) = h2 @ W2 via MFMA (R31 verified). R32: h2 arrives as
// bf16 (h2b) — staging is now a pure bit-copy (identical XA bits).
// Block = 64 nodes x 48 cols (40 real + 8 zero pad), K=64 = 2x32 steps.
__global__ __launch_bounds__(256) void k_xform2(const ushort_t* __restrict__ h2b,
                                                const float* __restrict__ W2,
                                                const float* __restrict__ asrc2,
                                                const float* __restrict__ adst2,
                                                ushort_t* __restrict__ gb,
                                                float* __restrict__ as2,
                                                float* __restrict__ ad2, int N) {
    __shared__ ushort_t XA[64 * 72];   // [node][k] bf16 (9.2KB)
    __shared__ ushort_t WB[48 * 72];   // [col][k]  bf16 (6.9KB)
    unsigned int* XAu = (unsigned int*)XA;
    int tid = threadIdx.x;
    int n0 = blockIdx.x * 64;
    // stage h2b (bf16) by bit-copy: 64 nodes x 8 uint4 (16B) chunks
    const uint4* h8 = (const uint4*)h2b;
    for (int i = tid; i < 512; i += 256) {
        int nd = i >> 3, q = i & 7;
        int gn = n0 + nd; if (gn > N - 1) gn = N - 1;
        uint4 v = h8[(size_t)gn * 8 + q];
        XAu[nd * 36 + 4 * q + 0] = v.x;
        XAu[nd * 36 + 4 * q + 1] = v.y;
        XAu[nd * 36 + 4 * q + 2] = v.z;
        XAu[nd * 36 + 4 * q + 3] = v.w;
    }
    // stage W2 transposed: WB[c][k] = W2[k][c]; cols 40..47 zero
    for (int i = tid; i < 48 * 64; i += 256) {
        int c = i >> 6, k = i & 63;
        float val = (c < 40) ? W2[k * 40 + c] : 0.f;
        WB[c * 72 + k] = (ushort_t)f2bf(val);
    }
    __syncthreads();
    int w = tid >> 6, l = tid & 63;
    int cl = l & 15;
    int arow = (w << 4) + cl;
    int kb0 = (l >> 4) << 3;
    f32x4 acc0 = {0.f, 0.f, 0.f, 0.f};
    f32x4 acc1 = acc0, acc2 = acc0;
    #pragma unroll
    for (int ks = 0; ks < 2; ks++) {
        int kb = kb0 + (ks << 5);
        bf16x8 af = *(const bf16x8*)&XA[arow * 72 + kb];
        bf16x8 b0 = *(const bf16x8*)&WB[(cl)      * 72 + kb];
        bf16x8 b1 = *(const bf16x8*)&WB[(16 + cl) * 72 + kb];
        bf16x8 b2 = *(const bf16x8*)&WB[(32 + cl) * 72 + kb];
        acc0 = __builtin_amdgcn_mfma_f32_16x16x32_bf16(af, b0, acc0, 0, 0, 0);
        acc1 = __builtin_amdgcn_mfma_f32_16x16x32_bf16(af, b1, acc1, 0, 0, 0);
        acc2 = __builtin_amdgcn_mfma_f32_16x16x32_bf16(af, b2, acc2, 0, 0, 0);
    }
    // epilogue: C layout col=cl (per tile), row=(l>>4)*4+reg
    int rbase = n0 + (w << 4) + ((l >> 4) << 2);
    int col0 = cl, col1 = 16 + cl, col2 = 32 + cl;
    float as0 = asrc2[col0], ad0 = adst2[col0];
    float as1c = asrc2[col1], ad1c = adst2[col1];
    float as2c = (col2 < 40) ? asrc2[col2] : 0.f;
    float ad2c = (col2 < 40) ? adst2[col2] : 0.f;
    #pragma unroll
    for (int r = 0; r < 4; r++) {
        int n = rbase + r;
        bool vn = n < N;
        if (vn) {
            gb[(size_t)n * 40 + col0] = (ushort_t)f2bf(acc0[r]);
            gb[(size_t)n * 40 + col1] = (ushort_t)f2bf(acc1[r]);
            if (col2 < 40) gb[(size_t)n * 40 + col2] = (ushort_t)f2bf(acc2[r]);
        }
        float s = acc0[r] * as0 + acc1[r] * as1c + acc2[r] * as2c;
        float dd = acc0[r] * ad0 + acc1[r] * ad1c + acc2[r] * ad2c;
        s += __shfl_xor(s, 1); s += __shfl_xor(s, 2);
        s += __shfl_xor(s, 4); s += __shfl_xor(s, 8);
        dd += __shfl_xor(dd, 1); dd += __shfl_xor(dd, 2);
        dd += __shfl_xor(dd, 4); dd += __shfl_xor(dd, 8);
        if (cl == 0 && vn) { as2[n] = s; ad2[n] = dd; }
    }
}

// 2-node agg2 gather. R32: cv pre-clamped at load — shfl by raw index
// (value-identical; old per-gather select removed).
#define AGG2_G(C_, SE_, AV_, UU_)                                            \
    int ee##C_ = 3 * (C_) + gg;                                              \
    int SE_ = __shfl(cv, nbase + ee##C_);                                    \
    SE_ = d > 0 ? SE_ : 0;                                                   \
    float AV_ = as2[SE_];                                                    \
    uint2 UU_ = *(const uint2*)(gbc + (unsigned)SE_ * 80u + poff);

#define AGG2_K(C_, AV_, UU_)                                                 \
    {                                                                        \
        float w_ = (ee##C_ < d) ? lrelu_exp(AV_ + add) : 0.f;                \
        acc[0] = fmaf(w_, bf_lo(UU_.x), acc[0]);                             \
        acc[1] = fmaf(w_, bf_hi(UU_.x), acc[1]);                             \
        acc[2] = fmaf(w_, bf_lo(UU_.y), acc[2]);                             \
        acc[3] = fmaf(w_, bf_hi(UU_.y), acc[3]);                             \
        z += w_;                                                             \
    }

// Layer-2 aggregation + bias + log_softmax. (R25-verified structure.)
__global__ __launch_bounds__(256) void k_agg2(const ushort_t* __restrict__ gb,
                                              const float* __restrict__ as2,
                                              const float* __restrict__ ad2,
                                              const float* __restrict__ b2,
                                              const int* __restrict__ rowptr,
                                              const int* __restrict__ rowEnd,
                                              const int* __restrict__ csr,
                                              float* __restrict__ out, int N) {
    int tid = threadIdx.x, lane = tid & 63;
    int nbase0 = blockIdx.x * 8 + ((tid >> 6) << 1);
    if (nbase0 >= N) return;              // wave-uniform
    int nid = lane >> 5;                  // node within wave (0/1)
    int nbase = nid << 5;                 // shfl base for this half
    int l32 = lane & 31;
    int gg = l32 / 10;                    // edge slot 0..2 (lanes 30/31 dup)
    int p = l32 - gg * 10;                // col block (4 cols each)
    if (gg > 2) { gg = 2; p = 9; }        // lanes 30,31: duplicate, unread
    int n = nbase0 + nid;
    bool valid = n < N;
    int nc = valid ? n : N - 1;
    const char* gbc = (const char*)gb;
    unsigned poff = (unsigned)p << 3;     // 8B per col block
    float add = ad2[nc];
    float acc[4] = {0.f, 0.f, 0.f, 0.f};
    float z = 0.f;

    int j0 = rowptr[nc], j1 = rowEnd[nc];
    int d = valid ? (j1 - j0) : 0;
    int dm1 = d > 0 ? d - 1 : 0;
    int dxx = __shfl_xor(d, 32);
    int dmax = d > dxx ? d : dxx;         // wave-uniform branch driver
    // ONE wave-wide csr load: lane e holds csr[e] if e<d else csr[dm1]
    int cv = csr[j0 + (l32 < d ? l32 : dm1)];

    {   // self loop (gg==0 lanes of each half)
        float w = lrelu_exp(as2[nc] + add);
        if (gg == 0 && valid) {
            uint2 u = *(const uint2*)(gbc + (unsigned)nc * 80u + poff);
            acc[0] = w * bf_lo(u.x); acc[1] = w * bf_hi(u.x);
            acc[2] = w * bf_lo(u.y); acc[3] = w * bf_hi(u.y);
            z = w;
        }
    }
    if (dmax > 0) {
        // gathers for chunks 0..7 (edges 0..23 per node), 1 round trip
        AGG2_G(0, s0, a0, u0)
        AGG2_G(1, s1, a1, u1)
        AGG2_G(2, s2, a2, u2)
        AGG2_G(3, s3, a3, u3)
        AGG2_G(4, s4, a4, u4)
        AGG2_G(5, s5, a5, u5)
        AGG2_G(6, s6, a6, u6)
        AGG2_G(7, s7, a7, u7)
        AGG2_K(0, a0, u0)
        if (dmax > 3)  AGG2_K(1, a1, u1)
        if (dmax > 6)  AGG2_K(2, a2, u2)
        if (dmax > 9)  AGG2_K(3, a3, u3)
        if (dmax > 12) AGG2_K(4, a4, u4)
        if (dmax > 15) AGG2_K(5, a5, u5)
        if (dmax > 18) AGG2_K(6, a6, u6)
        if (dmax > 21) AGG2_K(7, a7, u7)
        if (dmax > 24) {                  // chunks 8/9 (edges 24..29)
            AGG2_G(8, s8, a8, u8)
            AGG2_G(9, s9, a9, u9)
            AGG2_K(8, a8, u8)
            if (dmax > 27) AGG2_K(9, a9, u9)
            if (dmax > 30) {              // rare fallback: direct per-lane loads
                for (int eb = 30; eb < dmax; eb += 3) {
                    int e = eb + gg;
                    int idx = e < d ? e : dm1;
                    int se = csr[j0 + idx];
                    se = d > 0 ? se : 0;
                    float av = as2[se];
                    uint2 u = *(const uint2*)(gbc + (unsigned)se * 80u + poff);
                    float w = (e < d) ? lrelu_exp(av + add) : 0.f;
                    acc[0] = fmaf(w, bf_lo(u.x), acc[0]);
                    acc[1] = fmaf(w, bf_hi(u.x), acc[1]);
                    acc[2] = fmaf(w, bf_lo(u.y), acc[2]);
                    acc[3] = fmaf(w, bf_hi(u.y), acc[3]);
                    z += w;
                }
            }
        }
    }
    // reduce across the 3 slot groups: A(p) = v(p) + v(p+10) + v(p+20).
    // Both shfls read the ORIGINAL value; result valid at lanes p<10 of
    // each half (reads stay within the half there).
    #pragma unroll
    for (int k = 0; k < 4; k++) {
        float t1 = __shfl(acc[k], lane + 10);
        float t2 = __shfl(acc[k], lane + 20);
        acc[k] += t1 + t2;
    }
    {
        float t1 = __shfl(z, lane + 10);
        float t2 = __shfl(z, lane + 20);
        z += t1 + t2;
    }
    // epilogue: lanes l32<10 hold 4 logits each (cols 4p..4p+3);
    // butterfly over each half's first 16 lanes (xor 1/2/4/8 stays inside)
    bool act = (l32 < 10) && valid;
    float l[4];
    float mv = -INFINITY;
    if (act) {
        float inv = 1.f / (z + 1e-16f);
        #pragma unroll
        for (int k = 0; k < 4; k++) {
            l[k] = acc[k] * inv + b2[p * 4 + k];
            mv = fmaxf(mv, l[k]);
        }
    }
    mv = fmaxf(mv, __shfl_xor(mv, 1));
    mv = fmaxf(mv, __shfl_xor(mv, 2));
    mv = fmaxf(mv, __shfl_xor(mv, 4));
    mv = fmaxf(mv, __shfl_xor(mv, 8));
    float ev = 0.f;
    if (act) {
        #pragma unroll
        for (int k = 0; k < 4; k++) ev += __expf(l[k] - mv);
    }
    ev += __shfl_xor(ev, 1);
    ev += __shfl_xor(ev, 2);
    ev += __shfl_xor(ev, 4);
    ev += __shfl_xor(ev, 8);
    if (act) {
        float ls = mv + __logf(ev);
        float4* dp = (float4*)&out[(size_t)n * 40 + p * 4];
        dp[0] = make_float4(l[0] - ls, l[1] - ls, l[2] - ls, l[3] - ls);
    }
}

extern "C" void kernel_launch(void* const* d_in, const int* in_sizes, int n_in,
                              void* d_out, int out_size, void* d_ws, size_t ws_size,
                              hipStream_t stream) {
    const float* x    = (const float*)d_in[0];
    const float* topo = (const float*)d_in[1];
    const int*   ei   = (const int*)d_in[2];
    const float* W1   = (const float*)d_in[3];
    const float* a_s1 = (const float*)d_in[4];
    const float* a_d1 = (const float*)d_in[5];
    const float* b1   = (const float*)d_in[6];
    const float* W2   = (const float*)d_in[7];
    const float* a_s2 = (const float*)d_in[8];
    const float* a_d2 = (const float*)d_in[9];
    const float* b2   = (const float*)d_in[10];
    float* out = (float*)d_out;

    int N = in_sizes[0] / 128;
    int E = in_sizes[2] / 2;
    const int* esrc = ei;
    const int* edst = ei + E;
    int NBUK = (N + 255) / 256;
    size_t cap = (size_t)NBUK * BUK_CAP;

    char* ws = (char*)d_ws;
    size_t off = 0;
    auto alloc = [&](size_t bytes) -> void* {
        void* p = ws + off;
        off = (off + bytes + 255) & ~(size_t)255;
        return p;
    };
    ushort_t* h1b  = (ushort_t*)alloc((size_t)N * 64 * 2);
    float* as1     = (float*)alloc((size_t)N * 8 * 4);
    float* ad1     = (float*)alloc((size_t)N * 8 * 4);
    ushort_t* h2b  = (ushort_t*)alloc((size_t)N * 64 * 2);  // bf16 (R32)
    ushort_t* gb   = (ushort_t*)alloc((size_t)N * 40 * 2);  // 80B rows
    float* as2     = (float*)alloc((size_t)N * 4);
    float* ad2     = (float*)alloc((size_t)N * 4);
    int*   rowptr  = (int*)alloc((size_t)N * 4);
    int*   rowEnd  = (int*)alloc((size_t)N * 4);
    int*   csr     = (int*)alloc(cap * 4);
    unsigned int* tmp = (unsigned int*)alloc(cap * 4);
    int* gCursor   = (int*)alloc((size_t)NBUK * 4);

    hipMemsetAsync(gCursor, 0, (size_t)NBUK * 4, stream);  // count-based cursors
    int nbin = (E + BIN_CHUNK - 1) / BIN_CHUNK;
    k_bin<<<nbin, 256, 0, stream>>>(esrc, edst, gCursor, tmp, E, NBUK);
    k_fill2<<<NBUK, 512, 0, stream>>>(tmp, gCursor, rowptr, rowEnd, csr, N);

    int nbg = (N + 63) / 64;  // 64-node GEMM tiles
    int nb8 = (N + 7) / 8;    // 2 nodes/wave x 4 waves/block (agg kernels)
    k_xform1<<<nbg, 256, 0, stream>>>(x, topo, W1, a_s1, a_d1, h1b, as1, ad1, N);
    k_agg1<<<nb8, 256, 0, stream>>>(h1b, as1, ad1, b1, rowptr, rowEnd, csr, h2b, N);
    k_xform2<<<nbg, 256, 0, stream>>>(h2b, W2, a_s2, a_d2, gb, as2, ad2, N);
    k_agg2<<<nb8, 256, 0, stream>>>(gb, as2, ad2, b2, rowptr, rowEnd, csr, out, N);
}